// Round 10
// baseline (371.146 us; speedup 1.0000x reference)
//
#include <hip/hip_runtime.h>
#include <hip/hip_bf16.h>
#include <cstdint>
#include <cstddef>

typedef __attribute__((ext_vector_type(8))) short short8;
typedef __attribute__((ext_vector_type(4))) short s16x4;
typedef __attribute__((ext_vector_type(4))) float f32x4;

#define DEVI static __device__ __forceinline__

constexpr int NB   = 8;
constexpr int CDIM = 256;
constexpr int NTOK = 2304;          // 48*48
constexpr int BNT  = NB * NTOK;     // 18432
constexpr int HIDN = 512;
constexpr int RCAP = 4096;          // refine-list capacity
constexpr size_t BNTC = (size_t)BNT * CDIM;          // 4,718,592 elements
constexpr size_t KVSTR = (size_t)32 * NTOK * 64;     // q/k/vt per-z stride (elements)
constexpr size_t HSTR  = (size_t)BNT * 1024;         // hffn per-z stride (elements)

DEVI unsigned short f2bf(float f) {
  unsigned u = __builtin_bit_cast(unsigned, f);
  unsigned r = 0x7FFFu + ((u >> 16) & 1u);
  return (unsigned short)((u + r) >> 16);
}
DEVI float bf2f(unsigned short h) {
  unsigned u = ((unsigned)h) << 16;
  return __builtin_bit_cast(float, u);
}

// ---------------------------------------------------------------- weights->bf16
__global__ __launch_bounds__(256) void convert_weights(
    const float* __restrict__ miw, const float* __restrict__ mow,
    const float* __restrict__ mf1, const float* __restrict__ mf2,
    const float* __restrict__ viw, const float* __restrict__ vow,
    const float* __restrict__ vf1, const float* __restrict__ vf2,
    unsigned short* __restrict__ dst)
{
  int i = blockIdx.x * 256 + threadIdx.x;
  int m = i / 786432;
  int r = i % 786432;
  const float* src; int off;
  if      (r < 196608) { src = m ? viw : miw; off = r; }
  else if (r < 262144) { src = m ? vow : mow; off = r - 196608; }
  else if (r < 524288) { src = m ? vf1 : mf1; off = r - 262144; }
  else                 { src = m ? vf2 : mf2; off = r - 524288; }
  dst[i] = f2bf(src[off]);
}

// ---------------------------------------------------------------- agent W1 -> bf16x2 split [512][1024]
__global__ __launch_bounds__(256) void split_w_kernel(
    const float* __restrict__ w1, unsigned short* __restrict__ W2)
{
  int i = blockIdx.x * 256 + threadIdx.x;
  int n = i >> 9, k = i & 511;
  float v = w1[i];
  unsigned short hi = f2bf(v);
  float r1 = v - bf2f(hi);
  unsigned short mid = f2bf(r1);
  size_t base = (size_t)n * 1024 + k;
  W2[base] = hi; W2[base + 512] = mid;
}

// ---------------------------------------------------------------- x -> bf16 hi plane, pixel-major [BNT][512]
__global__ __launch_bounds__(256) void split_x_kernel(
    const float* __restrict__ f_ir, const float* __restrict__ f_vis,
    unsigned short* __restrict__ A2)
{
  __shared__ float tile[64][65];
  int n0 = blockIdx.x * 64, c0 = blockIdx.y * 64, b = blockIdx.z;
  int tid = threadIdx.x;
  const float* src = (c0 < 256) ? f_ir : f_vis;
  int cc0 = c0 & 255;
#pragma unroll
  for (int i = 0; i < 16; ++i) {
    int l = tid + i * 256;
    int r = l >> 6, col = l & 63;
    tile[r][col] = src[((size_t)b * 256 + cc0 + r) * NTOK + n0 + col];
  }
  __syncthreads();
#pragma unroll
  for (int i = 0; i < 16; ++i) {
    int l = tid + i * 256;
    int r = l >> 6, col = l & 63;
    A2[((size_t)b * NTOK + n0 + r) * 512 + c0 + col] = f2bf(tile[col][r]);
  }
}

// ---------------------------------------------------------------- agent GEMM (128x64) single-pass x_hi x (W_hi|W_mid) + fused epilogue
__global__ __launch_bounds__(256) void agent_gemm(
    const unsigned short* __restrict__ A2, const unsigned short* __restrict__ W2,
    const float* __restrict__ b1,
    const float* __restrict__ bng, const float* __restrict__ bnb,
    const float* __restrict__ bnm, const float* __restrict__ bnv,
    const float* __restrict__ w2, float* __restrict__ hpart)
{
  __shared__ unsigned short As[128][72];
  __shared__ unsigned short Ws[128][72];   // rows 0-63: W-hi, rows 64-127: W-mid
  __shared__ float scl[64], shl[64], w2l[64];
  int tid = threadIdx.x;
  int lane = tid & 63, wid = tid >> 6;
  int wm = (wid >> 1) * 64, wn = (wid & 1) * 32;
  int m0 = blockIdx.x * 128, n0 = blockIdx.y * 64;
  if (tid < 64) {
    int n = n0 + tid;
    double inv = 1.0 / sqrt((double)bnv[n] + 1e-5);
    double sc = (double)bng[n] * inv;
    scl[tid] = (float)sc;
    shl[tid] = (float)(((double)b1[n] - (double)bnm[n]) * sc + (double)bnb[n]);
    w2l[tid] = w2[n];
  }
  f32x4 zero = {0.f, 0.f, 0.f, 0.f};
  f32x4 acc[4][2];
#pragma unroll
  for (int i = 0; i < 4; ++i)
#pragma unroll
    for (int j = 0; j < 2; ++j) acc[i][j] = zero;

  for (int kin = 0; kin < 512; kin += 64) {
    __syncthreads();
#pragma unroll
    for (int i = 0; i < 4; ++i) {
      int l = tid + i * 256;
      int r = l >> 3, ch = (l & 7) * 8;
      *(short8*)&As[r][ch] = *(const short8*)&A2[(size_t)(m0 + r) * 512 + kin + ch];
    }
#pragma unroll
    for (int i = 0; i < 4; ++i) {
      int l = tid + i * 256;
      int r = l >> 3, ch = (l & 7) * 8;
      int wr = (r < 64) ? r : (r - 64);
      int wo = (r < 64) ? 0 : 512;
      *(short8*)&Ws[r][ch] = *(const short8*)&W2[(size_t)(n0 + wr) * 1024 + wo + kin + ch];
    }
    __syncthreads();
#pragma unroll
    for (int ks = 0; ks < 2; ++ks) {
      short8 a[4], bh[2], bm[2];
#pragma unroll
      for (int i = 0; i < 4; ++i)
        a[i] = *(const short8*)&As[wm + i * 16 + (lane & 15)][ks * 32 + (lane >> 4) * 8];
#pragma unroll
      for (int j = 0; j < 2; ++j) {
        bh[j] = *(const short8*)&Ws[wn + j * 16 + (lane & 15)][ks * 32 + (lane >> 4) * 8];
        bm[j] = *(const short8*)&Ws[64 + wn + j * 16 + (lane & 15)][ks * 32 + (lane >> 4) * 8];
      }
#pragma unroll
      for (int i = 0; i < 4; ++i)
#pragma unroll
        for (int j = 0; j < 2; ++j) {
          acc[i][j] = __builtin_amdgcn_mfma_f32_16x16x32_bf16(a[i], bh[j], acc[i][j], 0, 0, 0);
          acc[i][j] = __builtin_amdgcn_mfma_f32_16x16x32_bf16(a[i], bm[j], acc[i][j], 0, 0, 0);
        }
    }
  }

  int rbase = (lane >> 4) * 4;
  int cbase = lane & 15;
  float part[4][4];
#pragma unroll
  for (int i = 0; i < 4; ++i) {
#pragma unroll
    for (int r = 0; r < 4; ++r) {
      float p = 0.f;
#pragma unroll
      for (int j = 0; j < 2; ++j) {
        int nl = wn + j * 16 + cbase;
        float val = acc[i][j][r] * scl[nl] + shl[nl];
        if (val > 0.f) p += val * w2l[nl];
      }
      part[i][r] = p;
    }
  }
#pragma unroll
  for (int msk = 1; msk < 16; msk <<= 1) {
#pragma unroll
    for (int i = 0; i < 4; ++i)
#pragma unroll
      for (int r = 0; r < 4; ++r)
        part[i][r] += __shfl_xor(part[i][r], msk);
  }
  if (cbase == 0) {
    int slot = blockIdx.y * 2 + (wid & 1);
#pragma unroll
    for (int i = 0; i < 4; ++i)
#pragma unroll
      for (int r = 0; r < 4; ++r) {
        int mm = m0 + wm + i * 16 + rbase + r;
        hpart[(size_t)mm * 16 + slot] = part[i][r];
      }
  }
}

// ---------------------------------------------------------------- decide: partials -> w (sigmoid), mean -> t, flag window (wave-agg)
__global__ __launch_bounds__(256) void decide_kernel(
    const float* __restrict__ hpart, const float* __restrict__ b2,
    const float* __restrict__ hw1, const float* __restrict__ hb1,
    const float* __restrict__ hw2, const float* __restrict__ hb2,
    double* __restrict__ w64, float* __restrict__ w32, double* __restrict__ t64,
    int* __restrict__ rcount, int* __restrict__ rlist)
{
  __shared__ double red[256];
  __shared__ double tsh;
  int b = blockIdx.x, tid = threadIdx.x, lane = tid & 63;
  unsigned long long ltmask = (1ull << lane) - 1ull;
  double wloc[9];
  double s = 0.0;
#pragma unroll
  for (int c = 0; c < 9; ++c) {
    int pix = b * NTOK + c * 256 + tid;
    const float* hp = hpart + (size_t)pix * 16;
    double lg = (double)b2[0];
#pragma unroll
    for (int j = 0; j < 16; ++j) lg += (double)hp[j];
    double wd = 1.0 / (1.0 + exp(-lg));
    w64[pix] = wd; w32[pix] = (float)wd;
    wloc[c] = wd;
    s += wd;
  }
  red[tid] = s;
  __syncthreads();
  for (int st = 128; st; st >>= 1) {
    if (tid < st) red[tid] += red[tid + st];
    __syncthreads();
  }
  if (tid == 0) {
    double g = red[0] / 2304.0;
    double acc = (double)hb2[0];
    for (int j = 0; j < 16; ++j) {
      double hh = g * (double)hw1[j] + (double)hb1[j];
      hh = hh > 0.0 ? hh : 0.0;
      acc += hh * (double)hw2[j];
    }
    tsh = 1.0 / (1.0 + exp(-acc));
    t64[b] = tsh;
  }
  __syncthreads();
  double t = tsh;
#pragma unroll
  for (int c = 0; c < 9; ++c) {
    int flag = fabs(wloc[c] - t) < 8e-4 ? 1 : 0;
    unsigned long long ball = __ballot(flag);
    if (ball) {
      int leader = __ffsll((long long)ball) - 1;
      int base = 0;
      if (lane == leader) base = atomicAdd(rcount, __popcll(ball));
      base = __shfl(base, leader);
      if (flag) {
        int idx = base + __popcll(ball & ltmask);
        if (idx < RCAP) rlist[idx] = b * NTOK + c * 256 + tid;
      }
    }
  }
}

// ---------------------------------------------------------------- fp64 recompute, 4 pixels/block (w1 amortized)
__global__ __launch_bounds__(256) void refine_kernel(
    const float* __restrict__ f_ir, const float* __restrict__ f_vis,
    const float* __restrict__ w1, const float* __restrict__ b1,
    const float* __restrict__ bng, const float* __restrict__ bnb,
    const float* __restrict__ bnm, const float* __restrict__ bnv,
    const float* __restrict__ w2, const float* __restrict__ b2,
    const int* __restrict__ rlist, const int* __restrict__ rcount,
    double* __restrict__ w64, float* __restrict__ w32)
{
  int nr = rcount[0]; if (nr > RCAP) nr = RCAP;
  int p0 = blockIdx.x * 4;
  if (p0 >= nr) return;
  int npx = nr - p0; if (npx > 4) npx = 4;
  __shared__ double xs[4][512];
  __shared__ double scs[512], shs[512];
  __shared__ double lred[4][4];
  __shared__ int pixs[4];
  int tid = threadIdx.x, lane = tid & 63, wid = tid >> 6;
  if (tid < 4) pixs[tid] = rlist[p0 + (tid < npx ? tid : 0)];
#pragma unroll
  for (int h = 0; h < 2; ++h) {
    int o = tid + h * 256;
    double inv = 1.0 / sqrt((double)bnv[o] + 1e-5);
    double sc = (double)bng[o] * inv;
    scs[o] = sc;
    shs[o] = ((double)b1[o] - (double)bnm[o]) * sc + (double)bnb[o];
  }
  __syncthreads();
#pragma unroll
  for (int i = 0; i < 8; ++i) {
    int sidx = tid + i * 256;          // 0..2047 = 4 pixels x 512
    int p = sidx >> 9, kk = sidx & 511;
    int pix = pixs[p];
    int b = pix / NTOK, n = pix % NTOK;
    const float* fsrc = (kk < 256) ? f_ir : f_vis;
    xs[p][kk] = (double)fsrc[((size_t)b * 256 + (kk & 255)) * NTOK + n];
  }
  __syncthreads();
  double xp[4][8];
#pragma unroll
  for (int p = 0; p < 4; ++p)
#pragma unroll
    for (int j = 0; j < 8; ++j) xp[p][j] = xs[p][lane * 8 + j];
  double lg[4] = {0.0, 0.0, 0.0, 0.0};
  for (int oo = 0; oo < 128; oo += 2) {
    int o = wid * 128 + oo;
    double s[2][4] = {};
    const float* wr = w1 + (size_t)o * 512 + lane * 8;
#pragma unroll
    for (int t = 0; t < 2; ++t)
#pragma unroll
      for (int j = 0; j < 8; ++j) {
        double wv = (double)wr[t * 512 + j];
#pragma unroll
        for (int p = 0; p < 4; ++p)
          s[t][p] += wv * xp[p][j];
      }
#pragma unroll
    for (int m = 1; m < 64; m <<= 1)
#pragma unroll
      for (int t = 0; t < 2; ++t)
#pragma unroll
        for (int p = 0; p < 4; ++p)
          s[t][p] += __shfl_xor(s[t][p], m);
#pragma unroll
    for (int t = 0; t < 2; ++t) {
      int ot = o + t;
#pragma unroll
      for (int p = 0; p < 4; ++p) {
        double hv = s[t][p] * scs[ot] + shs[ot];
        if (hv > 0.0) lg[p] += hv * (double)w2[ot];
      }
    }
  }
  if (lane == 0)
#pragma unroll
    for (int p = 0; p < 4; ++p) lred[wid][p] = lg[p];
  __syncthreads();
  if (tid < npx) {
    int p = tid;
    double L = lred[0][p] + lred[1][p] + lred[2][p] + lred[3][p] + (double)b2[0];
    double wd = 1.0 / (1.0 + exp(-L));
    w64[pixs[p]] = wd;
    w32[pixs[p]] = (float)wd;
  }
}

// ---------------------------------------------------------------- compaction (mask+soft fused, top-64 fallback) + inverse map
__global__ __launch_bounds__(256) void compact_kernel(
    const double* __restrict__ w64, const double* __restrict__ t64,
    float* __restrict__ soft, int* __restrict__ active, int* __restrict__ actidx,
    int* __restrict__ invmap, int* __restrict__ nact, int* __restrict__ npad)
{
  __shared__ double wv[NTOK];
  __shared__ double rv[256];
  __shared__ int   ri[256];
  __shared__ int wtot[9][4];
  int b = blockIdx.x, tid = threadIdx.x, lane = tid & 63, wid = tid >> 6;
  double t = t64[b];
  unsigned long long ltmask = (1ull << lane) - 1ull;

  int sbase = 0;
  for (int c = 0; c < 9; ++c) {
    int i = c * 256 + tid;
    double wd = w64[(size_t)b * NTOK + i];
    double sd = 1.0 / (1.0 + exp(-(wd - t) * 50.0));
    soft[(size_t)b * NTOK + i] = (float)sd;
    int a = sd > 0.5 ? 1 : 0;
    active[(size_t)b * NTOK + i] = a;
    unsigned long long ball = __ballot(a);
    int wpre = __popcll(ball & ltmask);
    if (lane == 0) wtot[c][wid] = __popcll(ball);
    __syncthreads();
    int cross = 0;
    for (int w = 0; w < wid; ++w) cross += wtot[c][w];
    int slot = sbase + cross + wpre;
    if (a) actidx[(size_t)b * NTOK + slot] = i;
    invmap[(size_t)b * NTOK + i] = a ? slot : -1;
    sbase += wtot[c][0] + wtot[c][1] + wtot[c][2] + wtot[c][3];
  }

  if (sbase < 64) {
    for (int i = tid; i < NTOK; i += 256) {
      wv[i] = w64[(size_t)b * NTOK + i];
      active[(size_t)b * NTOK + i] = 0;
    }
    __syncthreads();
    for (int it = 0; it < 64; ++it) {
      double best = -1e300; int bi = 1 << 30;
      for (int i = tid; i < NTOK; i += 256) {
        double vvv = wv[i];
        if (vvv > best || (vvv == best && i < bi)) { best = vvv; bi = i; }
      }
      rv[tid] = best; ri[tid] = bi;
      __syncthreads();
      for (int st = 128; st; st >>= 1) {
        if (tid < st) {
          if (rv[tid + st] > rv[tid] ||
              (rv[tid + st] == rv[tid] && ri[tid + st] < ri[tid])) {
            rv[tid] = rv[tid + st]; ri[tid] = ri[tid + st];
          }
        }
        __syncthreads();
      }
      if (tid == 0) { active[(size_t)b * NTOK + ri[0]] = 1; wv[ri[0]] = -1e300; }
      __syncthreads();
    }
    sbase = 0;
    for (int c = 0; c < 9; ++c) {
      int i = c * 256 + tid;
      int a = active[(size_t)b * NTOK + i];
      unsigned long long ball = __ballot(a);
      int wpre = __popcll(ball & ltmask);
      if (lane == 0) wtot[c][wid] = __popcll(ball);
      __syncthreads();
      int cross = 0;
      for (int w = 0; w < wid; ++w) cross += wtot[c][w];
      int slot = sbase + cross + wpre;
      if (a) actidx[(size_t)b * NTOK + slot] = i;
      invmap[(size_t)b * NTOK + i] = a ? slot : -1;
      sbase += wtot[c][0] + wtot[c][1] + wtot[c][2] + wtot[c][3];
    }
  }
  int n = sbase;
  int np = (n + 127) & ~127;
  if (np > NTOK) np = NTOK;
  for (int i = n + tid; i < np; i += 256) actidx[(size_t)b * NTOK + i] = -1;
  if (tid == 0) { nact[b] = n; npad[b] = np; }
}

// ---------------------------------------------------------------- gather compact rows from x_hi (bf16 -> f32); z = ir/vis
__global__ __launch_bounds__(256) void gather_kernel(
    const unsigned short* __restrict__ A2, const int* __restrict__ actidx,
    const int* __restrict__ npad, float* __restrict__ xc)
{
  int b = blockIdx.y, i0 = blockIdx.x * 64, z = blockIdx.z;
  int cofs = z * 256;
  xc += (size_t)z * BNTC;
  if (i0 >= npad[b]) return;
  __shared__ int idx[64];
  int tid = threadIdx.x;
  if (tid < 64) idx[tid] = actidx[(size_t)b * NTOK + i0 + tid];
  __syncthreads();
#pragma unroll
  for (int it = 0; it < 16; ++it) {
    int s = tid + it * 256;
    int r = s >> 6, q4 = (s & 63) * 4;
    int src = idx[r];
    f32x4 v = {0.f, 0.f, 0.f, 0.f};
    if (src >= 0) {
      const unsigned short* p = A2 + ((size_t)b * NTOK + src) * 512 + cofs + q4;
      s16x4 hi = *(const s16x4*)&p[0];
#pragma unroll
      for (int j = 0; j < 4; ++j)
        v[j] = bf2f((unsigned short)hi[j]);
    }
    *(f32x4*)&xc[((size_t)b * NTOK + i0 + r) * 256 + q4] = v;
  }
}

// ---------------------------------------------------------------- LayerNorm, z via blockIdx.y
__global__ __launch_bounds__(256) void ln_kernel(
    const float* __restrict__ x, size_t xstr,
    const float* __restrict__ g0, const float* __restrict__ be0,
    const float* __restrict__ g1, const float* __restrict__ be1, int zbase,
    unsigned short* __restrict__ out, size_t ostr, const int* __restrict__ npad)
{
  int z = blockIdx.y;
  x += (size_t)z * xstr; out += (size_t)z * ostr;
  const float* gamma = ((zbase + z) & 1) ? g1 : g0;
  const float* beta  = ((zbase + z) & 1) ? be1 : be0;
  int lane = threadIdx.x & 63, wid = threadIdx.x >> 6;
  int tok = blockIdx.x * 4 + wid;
  int b = tok / NTOK;
  if ((tok - b * NTOK) >= npad[b]) return;
  const float* xp = x + (size_t)tok * 256;
  f32x4 v = *(const f32x4*)&xp[lane * 4];
  float s = v[0] + v[1] + v[2] + v[3];
#pragma unroll
  for (int m = 1; m < 64; m <<= 1) s += __shfl_xor(s, m);
  float mu = s * (1.f / 256.f);
  float vs = 0.f;
#pragma unroll
  for (int j = 0; j < 4; ++j) { float d = v[j] - mu; vs += d * d; }
#pragma unroll
  for (int m = 1; m < 64; m <<= 1) vs += __shfl_xor(vs, m);
  float rs = rsqrtf(vs * (1.f / 256.f) + 1e-5f);
  f32x4 gg = *(const f32x4*)&gamma[lane * 4];
  f32x4 bb = *(const f32x4*)&beta[lane * 4];
  unsigned short r0 = f2bf((v[0] - mu) * rs * gg[0] + bb[0]);
  unsigned short r1 = f2bf((v[1] - mu) * rs * gg[1] + bb[1]);
  unsigned short r2 = f2bf((v[2] - mu) * rs * gg[2] + bb[2]);
  unsigned short r3 = f2bf((v[3] - mu) * rs * gg[3] + bb[3]);
  uint2 pk;
  pk.x = (unsigned)r0 | ((unsigned)r1 << 16);
  pk.y = (unsigned)r2 | ((unsigned)r3 << 16);
  *(uint2*)&out[(size_t)tok * 256 + lane * 4] = pk;
}

// ---------------------------------------------------------------- bf16 GEMM on compact rows, z via blockIdx.z
// EPI: 0=qkv scatter, 1=proj+residual, 2=gelu->bf16, 3=ffn2+residual -> compact refined
template <int EPI>
__global__ __launch_bounds__(256) void gemm_bt(
    const unsigned short* __restrict__ A, size_t astr,
    const unsigned short* __restrict__ Wt, size_t wstr,
    const float* __restrict__ biasA, const float* __restrict__ biasB, int zbase,
    float* __restrict__ xres, size_t xstr,
    float* __restrict__ fout, size_t fstr,
    unsigned short* __restrict__ bout, size_t bstr,
    unsigned short* __restrict__ qb, unsigned short* __restrict__ kb,
    unsigned short* __restrict__ vtb, size_t qstr,
    const int* __restrict__ npad, int N, int K)
{
  int z = blockIdx.z;
  A += (size_t)z * astr;
  Wt += (size_t)z * wstr;
  const float* bias = ((zbase + z) & 1) ? biasB : biasA;
  if (EPI == 0) { qb += (size_t)z * qstr; kb += (size_t)z * qstr; vtb += (size_t)z * qstr; }
  if (EPI == 1 || EPI == 3) xres += (size_t)z * xstr;
  if (EPI == 3) fout += (size_t)z * fstr;
  if (EPI == 2) bout += (size_t)z * bstr;

  int m0 = blockIdx.x * 128, n0 = blockIdx.y * 128;
  int bb = m0 / NTOK;
  if ((m0 - bb * NTOK) >= npad[bb]) return;
  __shared__ unsigned short As[128][72];
  __shared__ unsigned short Ws[128][72];
  int tid = threadIdx.x;
  int lane = tid & 63, wid = tid >> 6;
  int wm = (wid >> 1) * 64, wn = (wid & 1) * 64;
  f32x4 zero = {0.f, 0.f, 0.f, 0.f};
  f32x4 acc[4][4];
#pragma unroll
  for (int i = 0; i < 4; ++i)
#pragma unroll
    for (int j = 0; j < 4; ++j) acc[i][j] = zero;

  for (int kc = 0; kc < K; kc += 64) {
#pragma unroll
    for (int i = 0; i < 4; ++i) {
      int l = tid + i * 256;
      int r = l >> 3, ch = (l & 7) * 8;
      *(short8*)&As[r][ch] = *(const short8*)&A[(size_t)(m0 + r) * K + kc + ch];
      *(short8*)&Ws[r][ch] = *(const short8*)&Wt[(size_t)(n0 + r) * K + kc + ch];
    }
    __syncthreads();
#pragma unroll
    for (int ks = 0; ks < 2; ++ks) {
      short8 a[4], bf[4];
#pragma unroll
      for (int i = 0; i < 4; ++i)
        a[i] = *(const short8*)&As[wm + i * 16 + (lane & 15)][ks * 32 + (lane >> 4) * 8];
#pragma unroll
      for (int j = 0; j < 4; ++j)
        bf[j] = *(const short8*)&Ws[wn + j * 16 + (lane & 15)][ks * 32 + (lane >> 4) * 8];
#pragma unroll
      for (int i = 0; i < 4; ++i)
#pragma unroll
        for (int j = 0; j < 4; ++j)
          acc[i][j] = __builtin_amdgcn_mfma_f32_16x16x32_bf16(a[i], bf[j], acc[i][j], 0, 0, 0);
    }
    __syncthreads();
  }

  int rbase = (lane >> 4) * 4;
  int cbase = lane & 15;
  if (EPI == 0) {
#pragma unroll
    for (int i = 0; i < 4; ++i) {
#pragma unroll
      for (int j = 0; j < 4; ++j) {
        int n = n0 + wn + j * 16 + cbase;
        int sect = n >> 8, hh = (n & 255) >> 6, d = n & 63;
        int mA = m0 + wm + i * 16 + rbase;
        int b = mA / NTOK, tok0 = mA % NTOK;
        size_t bh = (size_t)(b * 4 + hh);
        float vals[4];
#pragma unroll
        for (int r = 0; r < 4; ++r) vals[r] = acc[i][j][r] + bias[n];
        if (sect == 0) {
#pragma unroll
          for (int r = 0; r < 4; ++r)
            qb[(bh * NTOK + tok0 + r) * 64 + d] = f2bf(vals[r] * 0.125f);
        } else if (sect == 1) {
#pragma unroll
          for (int r = 0; r < 4; ++r)
            kb[(bh * NTOK + tok0 + r) * 64 + d] = f2bf(vals[r]);
        } else {
          unsigned short p0 = f2bf(vals[0]), p1 = f2bf(vals[1]);
          unsigned short p2 = f2bf(vals[2]), p3 = f2bf(vals[3]);
          uint2 pk;
          pk.x = (unsigned)p0 | ((unsigned)p1 << 16);
          pk.y = (unsigned)p2 | ((unsigned)p3 << 16);
          *(uint2*)&vtb[(bh * 64 + d) * NTOK + tok0] = pk;
        }
      }
    }
  } else {
#pragma unroll
    for (int i = 0; i < 4; ++i) {
#pragma unroll
      for (int j = 0; j < 4; ++j) {
#pragma unroll
        for (int r = 0; r < 4; ++r) {
          int m = m0 + wm + i * 16 + rbase + r;
          int n = n0 + wn + j * 16 + cbase;
          float v = acc[i][j][r] + bias[n];
          size_t idx = (size_t)m * N + n;
          if (EPI == 1) {
            xres[idx] += v;
          } else if (EPI == 2) {
            float g = 0.5f * v * (1.f + erff(v * 0.70710678118654752f));
            bout[idx] = f2bf(g);
          } else {
            fout[idx] = xres[idx] + v;
          }
        }
      }
    }
  }
}

// ---------------------------------------------------------------- flash attention over compact active keys, z via blockIdx.z
__global__ __launch_bounds__(256) void flash_kernel(
    const unsigned short* __restrict__ Q, const unsigned short* __restrict__ Kt,
    const unsigned short* __restrict__ VT, const int* __restrict__ nact,
    const int* __restrict__ npad, unsigned short* __restrict__ attnout)
{
  int z = blockIdx.z;
  Q += (size_t)z * KVSTR; Kt += (size_t)z * KVSTR; VT += (size_t)z * KVSTR;
  attnout += (size_t)z * BNTC;
  int bh = blockIdx.x, qt = blockIdx.y;
  int b = bh >> 2, h = bh & 3;
  int np = npad[b], na = nact[b];
  if (qt * 64 >= np) return;
  __shared__ unsigned short Ks[64][72];
  __shared__ unsigned short Vs[64][72];
  __shared__ unsigned short Ps[4][16][72];
  __shared__ float madd[64];
  int tid = threadIdx.x, lane = tid & 63, wid = tid >> 6;
  int qrow = qt * 64 + wid * 16 + (lane & 15);
  const unsigned short* qptr = Q + ((size_t)bh * NTOK + qrow) * 64;
  short8 aq0 = *(const short8*)&qptr[(lane >> 4) * 8];
  short8 aq1 = *(const short8*)&qptr[32 + (lane >> 4) * 8];
  f32x4 zero = {0.f, 0.f, 0.f, 0.f};
  f32x4 o[4];
  float mrow[4], lrow[4];
#pragma unroll
  for (int n = 0; n < 4; ++n) o[n] = zero;
#pragma unroll
  for (int r = 0; r < 4; ++r) { mrow[r] = -INFINITY; lrow[r] = 0.f; }
  const unsigned short* kbase = Kt + (size_t)bh * NTOK * 64;
  const unsigned short* vbase = VT + (size_t)bh * 64 * NTOK;
  int nkt = (na + 63) >> 6;

  for (int kt = 0; kt < nkt; ++kt) {
    int k0 = kt * 64;
#pragma unroll
    for (int i = 0; i < 2; ++i) {
      int l = tid + i * 256;
      int r = l >> 3, ch = (l & 7) * 8;
      *(short8*)&Ks[r][ch] = *(const short8*)&kbase[(size_t)(k0 + r) * 64 + ch];
      *(short8*)&Vs[r][ch] = *(const short8*)&vbase[(size_t)r * NTOK + k0 + ch];
    }
    if (tid < 64) madd[tid] = (k0 + tid < na) ? 0.f : -1e9f;
    __syncthreads();

    f32x4 s[4];
#pragma unroll
    for (int n = 0; n < 4; ++n) s[n] = zero;
#pragma unroll
    for (int n = 0; n < 4; ++n) {
      short8 bk0 = *(const short8*)&Ks[n * 16 + (lane & 15)][(lane >> 4) * 8];
      short8 bk1 = *(const short8*)&Ks[n * 16 + (lane & 15)][32 + (lane >> 4) * 8];
      s[n] = __builtin_amdgcn_mfma_f32_16x16x32_bf16(aq0, bk0, s[n], 0, 0, 0);
      s[n] = __builtin_amdgcn_mfma_f32_16x16x32_bf16(aq1, bk1, s[n], 0, 0, 0);
    }
    float pm[4] = {-INFINITY, -INFINITY, -INFINITY, -INFINITY};
#pragma unroll
    for (int n = 0; n < 4; ++n) {
      float ca = madd[n * 16 + (lane & 15)];
#pragma unroll
      for (int r = 0; r < 4; ++r) {
        s[n][r] += ca;
        pm[r] = fmaxf(pm[r], s[n][r]);
      }
    }
#pragma unroll
    for (int r = 0; r < 4; ++r) {
#pragma unroll
      for (int msk = 1; msk < 16; msk <<= 1)
        pm[r] = fmaxf(pm[r], __shfl_xor(pm[r], msk));
    }
    float sf[4], psum[4];
#pragma unroll
    for (int r = 0; r < 4; ++r) {
      float mn = fmaxf(mrow[r], pm[r]);
      sf[r] = __expf(mrow[r] - mn);
      mrow[r] = mn;
      psum[r] = 0.f;
    }
#pragma unroll
    for (int n = 0; n < 4; ++n)
#pragma unroll
      for (int r = 0; r < 4; ++r) {
        float p = __expf(s[n][r] - mrow[r]);
        s[n][r] = p;
        psum[r] += p;
      }
#pragma unroll
    for (int r = 0; r < 4; ++r) {
#pragma unroll
      for (int msk = 1; msk < 16; msk <<= 1)
        psum[r] += __shfl_xor(psum[r], msk);
      lrow[r] = lrow[r] * sf[r] + psum[r];
    }
#pragma unroll
    for (int n = 0; n < 4; ++n)
#pragma unroll
      for (int r = 0; r < 4; ++r) o[n][r] *= sf[r];
#pragma unroll
    for (int n = 0; n < 4; ++n)
#pragma unroll
      for (int r = 0; r < 4; ++r)
        Ps[wid][(lane >> 4) * 4 + r][n * 16 + (lane & 15)] = f2bf(s[n][r]);
    asm volatile("s_waitcnt lgkmcnt(0)" ::: "memory");
    __builtin_amdgcn_sched_barrier(0);
    short8 ap0 = *(const short8*)&Ps[wid][lane & 15][(lane >> 4) * 8];
    short8 ap1 = *(const short8*)&Ps[wid][lane & 15][32 + (lane >> 4) * 8];
#pragma unroll
    for (int n = 0; n < 4; ++n) {
      short8 bv0 = *(const short8*)&Vs[n * 16 + (lane & 15)][(lane >> 4) * 8];
      short8 bv1 = *(const short8*)&Vs[n * 16 + (lane & 15)][32 + (lane >> 4) * 8];
      o[n] = __builtin_amdgcn_mfma_f32_16x16x32_bf16(ap0, bv0, o[n], 0, 0, 0);
      o[n] = __builtin_amdgcn_mfma_f32_16x16x32_bf16(ap1, bv1, o[n], 0, 0, 0);
    }
    __syncthreads();
  }
#pragma unroll
  for (int n = 0; n < 4; ++n)
#pragma unroll
    for (int r = 0; r < 4; ++r) {
      int row = qt * 64 + wid * 16 + (lane >> 4) * 4 + r;
      int col = h * 64 + n * 16 + (lane & 15);
      float v = o[n][r] / lrow[r];
      attnout[((size_t)b * NTOK + row) * 256 + col] = f2bf(v);
    }
}

// ---------------------------------------------------------------- final scatter-back fusion (inverse-map gather)
__global__ __launch_bounds__(256) void final_kernel(
    const float* __restrict__ f_ir, const float* __restrict__ f_vis,
    const float* __restrict__ rirc, const float* __restrict__ rvisc,
    const float* __restrict__ w32, const float* __restrict__ soft,
    const int* __restrict__ invmap, const float* __restrict__ hs_ptr,
    float* __restrict__ out)
{
  __shared__ float tir[64][65], tvis[64][65];
  __shared__ float wl[64], sl[64];
  __shared__ int il[64];
  int n0 = blockIdx.x * 64, c0 = blockIdx.y * 64, b = blockIdx.z;
  int tid = threadIdx.x;
  float hs = hs_ptr[0];
  if (tid < 64) {
    int t = b * NTOK + n0 + tid;
    wl[tid] = w32[t]; sl[tid] = soft[t]; il[tid] = invmap[t];
  }
  __syncthreads();
#pragma unroll
  for (int i = 0; i < 16; ++i) {
    int l = tid + i * 256;
    int r = l >> 6, col = l & 63;
    int ci = il[r];
    if (ci >= 0) {
      size_t idx = ((size_t)b * NTOK + ci) * 256 + c0 + col;
      tir[r][col] = rirc[idx];
      tvis[r][col] = rvisc[idx];
    }
  }
  __syncthreads();
#pragma unroll
  for (int i = 0; i < 16; ++i) {
    int l = tid + i * 256;
    int r = l >> 6, col = l & 63;
    size_t gidx = ((size_t)b * 256 + c0 + r) * NTOK + n0 + col;
    float base = f_ir[gidx] + f_vis[gidx];
    float val;
    if (il[col] >= 0) {
      float ww = wl[col], ss = sl[col];
      float fusion = tir[col][r] * ww + tvis[col][r] * (1.f - ww);
      val = (base + fusion * ss) * (1.f + ss * hs);
    } else {
      val = base;
    }
    out[gidx] = val;
  }
  if (blockIdx.x == 0 && blockIdx.y == 0 && blockIdx.z == 0 && tid == 0)
    out[(size_t)NB * 256 * NTOK] = 0.f;   // aux_loss
}

// ================================================================ host
extern "C" void kernel_launch(void* const* d_in, const int* in_sizes, int n_in,
                              void* d_out, int out_size, void* d_ws, size_t ws_size,
                              hipStream_t stream)
{
  const float* f_ir     = (const float*)d_in[0];
  const float* f_vis    = (const float*)d_in[1];
  const float* agent_w1 = (const float*)d_in[2];
  const float* agent_b1 = (const float*)d_in[3];
  const float* bn_gamma = (const float*)d_in[4];
  const float* bn_beta  = (const float*)d_in[5];
  const float* bn_mean  = (const float*)d_in[6];
  const float* bn_var   = (const float*)d_in[7];
  const float* agent_w2 = (const float*)d_in[8];
  const float* agent_b2 = (const float*)d_in[9];
  const float* hyp_w1   = (const float*)d_in[10];
  const float* hyp_b1   = (const float*)d_in[11];
  const float* hyp_w2   = (const float*)d_in[12];
  const float* hyp_b2   = (const float*)d_in[13];
  int hs_idx = (in_sizes[14] == 1) ? 14 : 34;
  int mix0   = (in_sizes[14] == 1) ? 15 : 14;
  const float* hs_ptr = (const float*)d_in[hs_idx];
  const float* mir_ln_g = (const float*)d_in[mix0 + 0];
  const float* mir_ln_b = (const float*)d_in[mix0 + 1];
  const float* mir_in_w = (const float*)d_in[mix0 + 2];
  const float* mir_in_b = (const float*)d_in[mix0 + 3];
  const float* mir_out_w= (const float*)d_in[mix0 + 4];
  const float* mir_out_b= (const float*)d_in[mix0 + 5];
  const float* mir_f1_w = (const float*)d_in[mix0 + 6];
  const float* mir_f1_b = (const float*)d_in[mix0 + 7];
  const float* mir_f2_w = (const float*)d_in[mix0 + 8];
  const float* mir_f2_b = (const float*)d_in[mix0 + 9];
  const float* mvis_ln_g = (const float*)d_in[mix0 + 10];
  const float* mvis_ln_b = (const float*)d_in[mix0 + 11];
  const float* mvis_in_w = (const float*)d_in[mix0 + 12];
  const float* mvis_in_b = (const float*)d_in[mix0 + 13];
  const float* mvis_out_w= (const float*)d_in[mix0 + 14];
  const float* mvis_out_b= (const float*)d_in[mix0 + 15];
  const float* mvis_f1_w = (const float*)d_in[mix0 + 16];
  const float* mvis_f1_b = (const float*)d_in[mix0 + 17];
  const float* mvis_f2_w = (const float*)d_in[mix0 + 18];
  const float* mvis_f2_b = (const float*)d_in[mix0 + 19];

  auto padded = [](size_t bytes) { return (bytes + 255) & ~(size_t)255; };
  size_t need2 = padded(2 * BNTC * 4)
               + padded(2 * BNTC * 2)
               + 3 * padded(2 * KVSTR * 2)
               + padded(2 * BNTC * 2)
               + padded(2 * BNTC * 4)
               + padded((size_t)2 * 786432 * 2)
               + padded((size_t)512 * 1024 * 2)
               + padded((size_t)BNT * 16 * 4)
               + padded((size_t)BNT * 8)
               + padded(64) + padded(64)
               + 3 * padded((size_t)BNT * 4)
               + padded((size_t)RCAP * 4)
               + 2 * padded((size_t)BNT * 4)
               + 2 * padded(64);
  int zc = (ws_size >= need2 + (1 << 20)) ? 2 : 1;

  char* ws = (char*)d_ws;
  size_t off = 0;
  auto alloc = [&](size_t bytes) {
    size_t o = off;
    off = (off + bytes + 255) & ~(size_t)255;
    return o;
  };
  size_t o_xc    = alloc(2 * BNTC * 4);
  size_t o_xn    = alloc((size_t)zc * BNTC * 2);
  size_t o_q     = alloc((size_t)zc * KVSTR * 2);
  size_t o_k     = alloc((size_t)zc * KVSTR * 2);
  size_t o_vt    = alloc((size_t)zc * KVSTR * 2);
  size_t o_attn  = alloc((size_t)zc * BNTC * 2);
  size_t o_rr    = alloc(2 * BNTC * 4);
  size_t o_wbf   = alloc((size_t)2 * 786432 * 2);
  size_t o_w2s   = alloc((size_t)512 * 1024 * 2);
  size_t o_hp    = alloc((size_t)BNT * 16 * 4);
  size_t o_w64   = alloc((size_t)BNT * 8);
  size_t o_t64   = alloc(64);
  size_t o_count = alloc(64);
  size_t o_w32   = alloc((size_t)BNT * 4);
  size_t o_soft  = alloc((size_t)BNT * 4);
  size_t o_act   = alloc((size_t)BNT * 4);
  size_t o_rlist = alloc((size_t)RCAP * 4);
  size_t o_aidx  = alloc((size_t)BNT * 4);
  size_t o_inv   = alloc((size_t)BNT * 4);
  size_t o_nact  = alloc(64);
  size_t o_npad  = alloc(64);
  (void)n_in; (void)out_size;

  float*  xc   = (float*)(ws + o_xc);
  unsigned short* xn   = (unsigned short*)(ws + o_xn);
  unsigned short* q    = (unsigned short*)(ws + o_q);
  unsigned short* k    = (unsigned short*)(ws + o_k);
  unsigned short* vt   = (unsigned short*)(ws + o_vt);
  unsigned short* attn = (unsigned short*)(ws + o_attn);
  unsigned short* hffn = (unsigned short*)(ws + o_q);
  float*  rr   = (float*)(ws + o_rr);
  unsigned short* A2 = (unsigned short*)(ws + o_rr);   // x_hi [BNT][512]; dead before EPI3 writes
  unsigned short* wbf  = (unsigned short*)(ws + o_wbf);
  unsigned short* W2   = (unsigned short*)(ws + o_w2s);
  float*  hpart = (float*)(ws + o_hp);
  double* w64  = (double*)(ws + o_w64);
  double* t64  = (double*)(ws + o_t64);
  int*    cnt  = (int*)(ws + o_count);
  int*    rcount = cnt + 8;
  float*  w32  = (float*)(ws + o_w32);
  float*  soft = (float*)(ws + o_soft);
  int*    act  = (int*)(ws + o_act);
  int*    rlist = (int*)(ws + o_rlist);
  int*    aidx = (int*)(ws + o_aidx);
  int*    invm = (int*)(ws + o_inv);
  int*    nact = (int*)(ws + o_nact);
  int*    npad = (int*)(ws + o_npad);

  const unsigned short* mir_in  = wbf;
  const unsigned short* mir_out = wbf + 196608;
  const unsigned short* mir_f1  = wbf + 262144;
  const unsigned short* mir_f2  = wbf + 524288;
  const unsigned short* vis_in  = wbf + 786432;
  const unsigned short* vis_out = wbf + 786432 + 196608;
  const unsigned short* vis_f1  = wbf + 786432 + 262144;
  const unsigned short* vis_f2  = wbf + 786432 + 524288;

  // --- independent setup (off the decision chain)
  hipMemsetAsync(cnt, 0, 16 * sizeof(int), stream);
  convert_weights<<<6144, 256, 0, stream>>>(mir_in_w, mir_out_w, mir_f1_w, mir_f2_w,
                                            mvis_in_w, mvis_out_w, mvis_f1_w, mvis_f2_w,
                                            wbf);
  split_w_kernel<<<1024, 256, 0, stream>>>(agent_w1, W2);
  split_x_kernel<<<dim3(36, 8, 8), 256, 0, stream>>>(f_ir, f_vis, A2);

  // --- agent decision chain
  agent_gemm<<<dim3(BNT / 128, 8), 256, 0, stream>>>(
      A2, W2, agent_b1, bn_gamma, bn_beta, bn_mean, bn_var, agent_w2, hpart);
  decide_kernel<<<8, 256, 0, stream>>>(
      hpart, agent_b2, hyp_w1, hyp_b1, hyp_w2, hyp_b2, w64, w32, t64, rcount, rlist);
  refine_kernel<<<RCAP / 4, 256, 0, stream>>>(
      f_ir, f_vis, agent_w1, agent_b1, bn_gamma, bn_beta, bn_mean, bn_var,
      agent_w2, agent_b2, rlist, rcount, w64, w32);
  compact_kernel<<<8, 256, 0, stream>>>(w64, t64, soft, act, aidx, invm, nact, npad);

  // --- gather both compact residual streams (z: 0=ir, 1=vis)
  gather_kernel<<<dim3(36, 8, 2), 256, 0, stream>>>(A2, aidx, npad, xc);

  if (zc == 2) {
    size_t WSTR = 786432;
    ln_kernel<<<dim3(BNT / 4, 2), 256, 0, stream>>>(
        xc, BNTC, mir_ln_g, mir_ln_b, mvis_ln_g, mvis_ln_b, 0, xn, BNTC, npad);
    gemm_bt<0><<<dim3(BNT / 128, 6, 2), 256, 0, stream>>>(
        xn, BNTC, mir_in, WSTR, mir_in_b, mvis_in_b, 0,
        nullptr, 0, nullptr, 0, nullptr, 0, q, k, vt, KVSTR, npad, 768, 256);
    flash_kernel<<<dim3(32, 36, 2), 256, 0, stream>>>(q, k, vt, nact, npad, attn);
    gemm_bt<1><<<dim3(BNT / 128, 2, 2), 256, 0, stream>>>(
        attn, BNTC, mir_out, WSTR, mir_out_b, mvis_out_b, 0,
        xc, BNTC, nullptr, 0, nullptr, 0, nullptr, nullptr, nullptr, 0, npad, 256, 256);
    ln_kernel<<<dim3(BNT / 4, 2), 256, 0, stream>>>(
        xc, BNTC, mir_ln_g, mir_ln_b, mvis_ln_g, mvis_ln_b, 0, xn, BNTC, npad);
    gemm_bt<2><<<dim3(BNT / 128, 8, 2), 256, 0, stream>>>(
        xn, BNTC, mir_f1, WSTR, mir_f1_b, mvis_f1_b, 0,
        nullptr, 0, nullptr, 0, hffn, HSTR, nullptr, nullptr, nullptr, 0, npad, 1024, 256);
    gemm_bt<3><<<dim3(BNT / 128, 2, 2), 256, 0, stream>>>(
        hffn, HSTR, mir_f2, WSTR, mir_f2_b, mvis_f2_b, 0,
        xc, BNTC, rr, BNTC, nullptr, 0, nullptr, nullptr, nullptr, 0, npad, 256, 1024);
  } else {
    for (int s = 0; s < 2; ++s) {
      const float* g   = s ? mvis_ln_g : mir_ln_g;
      const float* be  = s ? mvis_ln_b : mir_ln_b;
      const unsigned short* w_in  = s ? vis_in  : mir_in;
      const unsigned short* w_out = s ? vis_out : mir_out;
      const unsigned short* w_f1  = s ? vis_f1  : mir_f1;
      const unsigned short* w_f2  = s ? vis_f2  : mir_f2;
      const float* b_in  = s ? mvis_in_b  : mir_in_b;
      const float* b_out = s ? mvis_out_b : mir_out_b;
      const float* b_f1  = s ? mvis_f1_b  : mir_f1_b;
      const float* b_f2  = s ? mvis_f2_b  : mir_f2_b;
      float* xcs = xc + (size_t)s * BNTC;
      float* rrs = rr + (size_t)s * BNTC;
      ln_kernel<<<dim3(BNT / 4, 1), 256, 0, stream>>>(
          xcs, 0, g, be, g, be, 0, xn, 0, npad);
      gemm_bt<0><<<dim3(BNT / 128, 6, 1), 256, 0, stream>>>(
          xn, 0, w_in, 0, b_in, b_in, 0,
          nullptr, 0, nullptr, 0, nullptr, 0, q, k, vt, 0, npad, 768, 256);
      flash_kernel<<<dim3(32, 36, 1), 256, 0, stream>>>(q, k, vt, nact, npad, attn);
      gemm_bt<1><<<dim3(BNT / 128, 2, 1), 256, 0, stream>>>(
          attn, 0, w_out, 0, b_out, b_out, 0,
          xcs, 0, nullptr, 0, nullptr, 0, nullptr, nullptr, nullptr, 0, npad, 256, 256);
      ln_kernel<<<dim3(BNT / 4, 1), 256, 0, stream>>>(
          xcs, 0, g, be, g, be, 0, xn, 0, npad);
      gemm_bt<2><<<dim3(BNT / 128, 8, 1), 256, 0, stream>>>(
          xn, 0, w_f1, 0, b_f1, b_f1, 0,
          nullptr, 0, nullptr, 0, hffn, 0, nullptr, nullptr, nullptr, 0, npad, 1024, 256);
      gemm_bt<3><<<dim3(BNT / 128, 2, 1), 256, 0, stream>>>(
          hffn, 0, w_f2, 0, b_f2, b_f2, 0,
          xcs, 0, rrs, 0, nullptr, 0, nullptr, nullptr, nullptr, 0, npad, 256, 1024);
    }
  }

  // --- final fusion + aux loss
  final_kernel<<<dim3(36, 4, 8), 256, 0, stream>>>(
      f_ir, f_vis, rr, rr + BNTC, w32, soft, invm, hs_ptr, (float*)d_out);
}

// Round 11
// 252.351 us; speedup vs baseline: 1.4708x; 1.4708x over previous
//
#include <hip/hip_runtime.h>
#include <hip/hip_bf16.h>
#include <cstdint>
#include <cstddef>

typedef __attribute__((ext_vector_type(8))) short short8;
typedef __attribute__((ext_vector_type(4))) short s16x4;
typedef __attribute__((ext_vector_type(4))) float f32x4;

#define DEVI static __device__ __forceinline__

constexpr int NB   = 8;
constexpr int CDIM = 256;
constexpr int NTOK = 2304;          // 48*48
constexpr int BNT  = NB * NTOK;     // 18432
constexpr int HIDN = 512;
constexpr int RCAP = 4096;          // refine-list capacity
constexpr size_t BNTC = (size_t)BNT * CDIM;          // 4,718,592 elements
constexpr size_t KVSTR = (size_t)32 * NTOK * 64;     // q/k/vt per-z stride (elements)
constexpr size_t HSTR  = (size_t)BNT * 1024;         // hffn per-z stride (elements)

DEVI unsigned short f2bf(float f) {
  unsigned u = __builtin_bit_cast(unsigned, f);
  unsigned r = 0x7FFFu + ((u >> 16) & 1u);
  return (unsigned short)((u + r) >> 16);
}
DEVI float bf2f(unsigned short h) {
  unsigned u = ((unsigned)h) << 16;
  return __builtin_bit_cast(float, u);
}

// ---------------------------------------------------------------- weights->bf16
__global__ __launch_bounds__(256) void convert_weights(
    const float* __restrict__ miw, const float* __restrict__ mow,
    const float* __restrict__ mf1, const float* __restrict__ mf2,
    const float* __restrict__ viw, const float* __restrict__ vow,
    const float* __restrict__ vf1, const float* __restrict__ vf2,
    unsigned short* __restrict__ dst)
{
  int i = blockIdx.x * 256 + threadIdx.x;
  int m = i / 786432;
  int r = i % 786432;
  const float* src; int off;
  if      (r < 196608) { src = m ? viw : miw; off = r; }
  else if (r < 262144) { src = m ? vow : mow; off = r - 196608; }
  else if (r < 524288) { src = m ? vf1 : mf1; off = r - 262144; }
  else                 { src = m ? vf2 : mf2; off = r - 524288; }
  dst[i] = f2bf(src[off]);
}

// ---------------------------------------------------------------- agent W1 -> bf16x2 split [512][1024]
__global__ __launch_bounds__(256) void split_w_kernel(
    const float* __restrict__ w1, unsigned short* __restrict__ W2)
{
  int i = blockIdx.x * 256 + threadIdx.x;
  int n = i >> 9, k = i & 511;
  float v = w1[i];
  unsigned short hi = f2bf(v);
  float r1 = v - bf2f(hi);
  unsigned short mid = f2bf(r1);
  size_t base = (size_t)n * 1024 + k;
  W2[base] = hi; W2[base + 512] = mid;
}

// ---------------------------------------------------------------- x -> bf16 hi plane, pixel-major [BNT][512]
__global__ __launch_bounds__(256) void split_x_kernel(
    const float* __restrict__ f_ir, const float* __restrict__ f_vis,
    unsigned short* __restrict__ A2)
{
  __shared__ float tile[64][65];
  int n0 = blockIdx.x * 64, c0 = blockIdx.y * 64, b = blockIdx.z;
  int tid = threadIdx.x;
  const float* src = (c0 < 256) ? f_ir : f_vis;
  int cc0 = c0 & 255;
#pragma unroll
  for (int i = 0; i < 16; ++i) {
    int l = tid + i * 256;
    int r = l >> 6, col = l & 63;
    tile[r][col] = src[((size_t)b * 256 + cc0 + r) * NTOK + n0 + col];
  }
  __syncthreads();
#pragma unroll
  for (int i = 0; i < 16; ++i) {
    int l = tid + i * 256;
    int r = l >> 6, col = l & 63;
    A2[((size_t)b * NTOK + n0 + r) * 512 + c0 + col] = f2bf(tile[col][r]);
  }
}

// ---------------------------------------------------------------- agent GEMM (128x64) single-pass x_hi x (W_hi|W_mid) + fused epilogue
__global__ __launch_bounds__(256) void agent_gemm(
    const unsigned short* __restrict__ A2, const unsigned short* __restrict__ W2,
    const float* __restrict__ b1,
    const float* __restrict__ bng, const float* __restrict__ bnb,
    const float* __restrict__ bnm, const float* __restrict__ bnv,
    const float* __restrict__ w2, float* __restrict__ hpart)
{
  __shared__ unsigned short As[128][72];
  __shared__ unsigned short Ws[128][72];   // rows 0-63: W-hi, rows 64-127: W-mid
  __shared__ float scl[64], shl[64], w2l[64];
  int tid = threadIdx.x;
  int lane = tid & 63, wid = tid >> 6;
  int wm = (wid >> 1) * 64, wn = (wid & 1) * 32;
  int m0 = blockIdx.x * 128, n0 = blockIdx.y * 64;
  if (tid < 64) {
    int n = n0 + tid;
    double inv = 1.0 / sqrt((double)bnv[n] + 1e-5);
    double sc = (double)bng[n] * inv;
    scl[tid] = (float)sc;
    shl[tid] = (float)(((double)b1[n] - (double)bnm[n]) * sc + (double)bnb[n]);
    w2l[tid] = w2[n];
  }
  f32x4 zero = {0.f, 0.f, 0.f, 0.f};
  f32x4 acc[4][2];
#pragma unroll
  for (int i = 0; i < 4; ++i)
#pragma unroll
    for (int j = 0; j < 2; ++j) acc[i][j] = zero;

  for (int kin = 0; kin < 512; kin += 64) {
    __syncthreads();
#pragma unroll
    for (int i = 0; i < 4; ++i) {
      int l = tid + i * 256;
      int r = l >> 3, ch = (l & 7) * 8;
      *(short8*)&As[r][ch] = *(const short8*)&A2[(size_t)(m0 + r) * 512 + kin + ch];
    }
#pragma unroll
    for (int i = 0; i < 4; ++i) {
      int l = tid + i * 256;
      int r = l >> 3, ch = (l & 7) * 8;
      int wr = (r < 64) ? r : (r - 64);
      int wo = (r < 64) ? 0 : 512;
      *(short8*)&Ws[r][ch] = *(const short8*)&W2[(size_t)(n0 + wr) * 1024 + wo + kin + ch];
    }
    __syncthreads();
#pragma unroll
    for (int ks = 0; ks < 2; ++ks) {
      short8 a[4], bh[2], bm[2];
#pragma unroll
      for (int i = 0; i < 4; ++i)
        a[i] = *(const short8*)&As[wm + i * 16 + (lane & 15)][ks * 32 + (lane >> 4) * 8];
#pragma unroll
      for (int j = 0; j < 2; ++j) {
        bh[j] = *(const short8*)&Ws[wn + j * 16 + (lane & 15)][ks * 32 + (lane >> 4) * 8];
        bm[j] = *(const short8*)&Ws[64 + wn + j * 16 + (lane & 15)][ks * 32 + (lane >> 4) * 8];
      }
#pragma unroll
      for (int i = 0; i < 4; ++i)
#pragma unroll
        for (int j = 0; j < 2; ++j) {
          acc[i][j] = __builtin_amdgcn_mfma_f32_16x16x32_bf16(a[i], bh[j], acc[i][j], 0, 0, 0);
          acc[i][j] = __builtin_amdgcn_mfma_f32_16x16x32_bf16(a[i], bm[j], acc[i][j], 0, 0, 0);
        }
    }
  }

  int rbase = (lane >> 4) * 4;
  int cbase = lane & 15;
  float part[4][4];
#pragma unroll
  for (int i = 0; i < 4; ++i) {
#pragma unroll
    for (int r = 0; r < 4; ++r) {
      float p = 0.f;
#pragma unroll
      for (int j = 0; j < 2; ++j) {
        int nl = wn + j * 16 + cbase;
        float val = acc[i][j][r] * scl[nl] + shl[nl];
        if (val > 0.f) p += val * w2l[nl];
      }
      part[i][r] = p;
    }
  }
#pragma unroll
  for (int msk = 1; msk < 16; msk <<= 1) {
#pragma unroll
    for (int i = 0; i < 4; ++i)
#pragma unroll
      for (int r = 0; r < 4; ++r)
        part[i][r] += __shfl_xor(part[i][r], msk);
  }
  if (cbase == 0) {
    int slot = blockIdx.y * 2 + (wid & 1);
#pragma unroll
    for (int i = 0; i < 4; ++i)
#pragma unroll
      for (int r = 0; r < 4; ++r) {
        int mm = m0 + wm + i * 16 + rbase + r;
        hpart[(size_t)mm * 16 + slot] = part[i][r];
      }
  }
}

// ---------------------------------------------------------------- decide: partials -> w (sigmoid), mean -> t, flag window (wave-agg)
__global__ __launch_bounds__(256) void decide_kernel(
    const float* __restrict__ hpart, const float* __restrict__ b2,
    const float* __restrict__ hw1, const float* __restrict__ hb1,
    const float* __restrict__ hw2, const float* __restrict__ hb2,
    double* __restrict__ w64, float* __restrict__ w32, double* __restrict__ t64,
    int* __restrict__ rcount, int* __restrict__ rlist)
{
  __shared__ double red[256];
  __shared__ double tsh;
  int b = blockIdx.x, tid = threadIdx.x, lane = tid & 63;
  unsigned long long ltmask = (1ull << lane) - 1ull;
  double wloc[9];
  double s = 0.0;
#pragma unroll
  for (int c = 0; c < 9; ++c) {
    int pix = b * NTOK + c * 256 + tid;
    const float* hp = hpart + (size_t)pix * 16;
    double lg = (double)b2[0];
#pragma unroll
    for (int j = 0; j < 16; ++j) lg += (double)hp[j];
    double wd = 1.0 / (1.0 + exp(-lg));
    w64[pix] = wd; w32[pix] = (float)wd;
    wloc[c] = wd;
    s += wd;
  }
  red[tid] = s;
  __syncthreads();
  for (int st = 128; st; st >>= 1) {
    if (tid < st) red[tid] += red[tid + st];
    __syncthreads();
  }
  if (tid == 0) {
    double g = red[0] / 2304.0;
    double acc = (double)hb2[0];
    for (int j = 0; j < 16; ++j) {
      double hh = g * (double)hw1[j] + (double)hb1[j];
      hh = hh > 0.0 ? hh : 0.0;
      acc += hh * (double)hw2[j];
    }
    tsh = 1.0 / (1.0 + exp(-acc));
    t64[b] = tsh;
  }
  __syncthreads();
  double t = tsh;
#pragma unroll
  for (int c = 0; c < 9; ++c) {
    int flag = fabs(wloc[c] - t) < 4e-4 ? 1 : 0;
    unsigned long long ball = __ballot(flag);
    if (ball) {
      int leader = __ffsll((long long)ball) - 1;
      int base = 0;
      if (lane == leader) base = atomicAdd(rcount, __popcll(ball));
      base = __shfl(base, leader);
      if (flag) {
        int idx = base + __popcll(ball & ltmask);
        if (idx < RCAP) rlist[idx] = b * NTOK + c * 256 + tid;
      }
    }
  }
}

// ---------------------------------------------------------------- fp64 recompute of flagged pixels (1 pixel/block, 8-way ILP)
__global__ __launch_bounds__(256) void refine_kernel(
    const float* __restrict__ f_ir, const float* __restrict__ f_vis,
    const float* __restrict__ w1, const float* __restrict__ b1,
    const float* __restrict__ bng, const float* __restrict__ bnb,
    const float* __restrict__ bnm, const float* __restrict__ bnv,
    const float* __restrict__ w2, const float* __restrict__ b2,
    const int* __restrict__ rlist, const int* __restrict__ rcount,
    double* __restrict__ w64, float* __restrict__ w32)
{
  int nr = rcount[0]; if (nr > RCAP) nr = RCAP;
  if ((int)blockIdx.x >= nr) return;
  int pix = rlist[blockIdx.x];
  int b = pix / NTOK, n = pix % NTOK;
  __shared__ double xs[512];
  __shared__ double scs[512], shs[512];
  __shared__ double lred[4];
  int tid = threadIdx.x, lane = tid & 63, wid = tid >> 6;
  xs[tid]       = (double)f_ir [((size_t)b * 256 + tid) * NTOK + n];
  xs[256 + tid] = (double)f_vis[((size_t)b * 256 + tid) * NTOK + n];
#pragma unroll
  for (int h = 0; h < 2; ++h) {
    int o = tid + h * 256;
    double inv = 1.0 / sqrt((double)bnv[o] + 1e-5);
    double sc = (double)bng[o] * inv;
    scs[o] = sc;
    shs[o] = ((double)b1[o] - (double)bnm[o]) * sc + (double)bnb[o];
  }
  __syncthreads();
  double xp[8];
#pragma unroll
  for (int j = 0; j < 8; ++j) xp[j] = xs[lane * 8 + j];
  double lg = 0.0;
  for (int oo = 0; oo < 128; oo += 8) {
    int o = wid * 128 + oo;
    double s[8] = {0, 0, 0, 0, 0, 0, 0, 0};
    const float* wr = w1 + (size_t)o * 512 + lane * 8;
#pragma unroll
    for (int t = 0; t < 8; ++t) {
#pragma unroll
      for (int j = 0; j < 8; ++j)
        s[t] += (double)wr[t * 512 + j] * xp[j];
    }
#pragma unroll
    for (int m = 1; m < 64; m <<= 1) {
#pragma unroll
      for (int t = 0; t < 8; ++t) s[t] += __shfl_xor(s[t], m);
    }
#pragma unroll
    for (int t = 0; t < 8; ++t) {
      int ot = o + t;
      double hv = s[t] * scs[ot] + shs[ot];
      if (hv > 0.0) lg += hv * (double)w2[ot];
    }
  }
  if (lane == 0) lred[wid] = lg;
  __syncthreads();
  if (tid == 0) {
    double L = lred[0] + lred[1] + lred[2] + lred[3] + (double)b2[0];
    double wd = 1.0 / (1.0 + exp(-L));
    w64[pix] = wd;
    w32[pix] = (float)wd;
  }
}

// ---------------------------------------------------------------- compaction (mask+soft fused, top-64 fallback) + inverse map
__global__ __launch_bounds__(256) void compact_kernel(
    const double* __restrict__ w64, const double* __restrict__ t64,
    float* __restrict__ soft, int* __restrict__ active, int* __restrict__ actidx,
    int* __restrict__ invmap, int* __restrict__ nact, int* __restrict__ npad)
{
  __shared__ double wv[NTOK];
  __shared__ double rv[256];
  __shared__ int   ri[256];
  __shared__ int wtot[9][4];
  int b = blockIdx.x, tid = threadIdx.x, lane = tid & 63, wid = tid >> 6;
  double t = t64[b];
  unsigned long long ltmask = (1ull << lane) - 1ull;

  int sbase = 0;
  for (int c = 0; c < 9; ++c) {
    int i = c * 256 + tid;
    double wd = w64[(size_t)b * NTOK + i];
    double sd = 1.0 / (1.0 + exp(-(wd - t) * 50.0));
    soft[(size_t)b * NTOK + i] = (float)sd;
    int a = sd > 0.5 ? 1 : 0;
    active[(size_t)b * NTOK + i] = a;
    unsigned long long ball = __ballot(a);
    int wpre = __popcll(ball & ltmask);
    if (lane == 0) wtot[c][wid] = __popcll(ball);
    __syncthreads();
    int cross = 0;
    for (int w = 0; w < wid; ++w) cross += wtot[c][w];
    int slot = sbase + cross + wpre;
    if (a) actidx[(size_t)b * NTOK + slot] = i;
    invmap[(size_t)b * NTOK + i] = a ? slot : -1;
    sbase += wtot[c][0] + wtot[c][1] + wtot[c][2] + wtot[c][3];
  }

  if (sbase < 64) {
    for (int i = tid; i < NTOK; i += 256) {
      wv[i] = w64[(size_t)b * NTOK + i];
      active[(size_t)b * NTOK + i] = 0;
    }
    __syncthreads();
    for (int it = 0; it < 64; ++it) {
      double best = -1e300; int bi = 1 << 30;
      for (int i = tid; i < NTOK; i += 256) {
        double vvv = wv[i];
        if (vvv > best || (vvv == best && i < bi)) { best = vvv; bi = i; }
      }
      rv[tid] = best; ri[tid] = bi;
      __syncthreads();
      for (int st = 128; st; st >>= 1) {
        if (tid < st) {
          if (rv[tid + st] > rv[tid] ||
              (rv[tid + st] == rv[tid] && ri[tid + st] < ri[tid])) {
            rv[tid] = rv[tid + st]; ri[tid] = ri[tid + st];
          }
        }
        __syncthreads();
      }
      if (tid == 0) { active[(size_t)b * NTOK + ri[0]] = 1; wv[ri[0]] = -1e300; }
      __syncthreads();
    }
    sbase = 0;
    for (int c = 0; c < 9; ++c) {
      int i = c * 256 + tid;
      int a = active[(size_t)b * NTOK + i];
      unsigned long long ball = __ballot(a);
      int wpre = __popcll(ball & ltmask);
      if (lane == 0) wtot[c][wid] = __popcll(ball);
      __syncthreads();
      int cross = 0;
      for (int w = 0; w < wid; ++w) cross += wtot[c][w];
      int slot = sbase + cross + wpre;
      if (a) actidx[(size_t)b * NTOK + slot] = i;
      invmap[(size_t)b * NTOK + i] = a ? slot : -1;
      sbase += wtot[c][0] + wtot[c][1] + wtot[c][2] + wtot[c][3];
    }
  }
  int n = sbase;
  int np = (n + 127) & ~127;
  if (np > NTOK) np = NTOK;
  for (int i = n + tid; i < np; i += 256) actidx[(size_t)b * NTOK + i] = -1;
  if (tid == 0) { nact[b] = n; npad[b] = np; }
}

// ---------------------------------------------------------------- gather compact rows from x_hi (bf16 -> f32); z = ir/vis
__global__ __launch_bounds__(256) void gather_kernel(
    const unsigned short* __restrict__ A2, const int* __restrict__ actidx,
    const int* __restrict__ npad, float* __restrict__ xc)
{
  int b = blockIdx.y, i0 = blockIdx.x * 64, z = blockIdx.z;
  int cofs = z * 256;
  xc += (size_t)z * BNTC;
  if (i0 >= npad[b]) return;
  __shared__ int idx[64];
  int tid = threadIdx.x;
  if (tid < 64) idx[tid] = actidx[(size_t)b * NTOK + i0 + tid];
  __syncthreads();
#pragma unroll
  for (int it = 0; it < 16; ++it) {
    int s = tid + it * 256;
    int r = s >> 6, q4 = (s & 63) * 4;
    int src = idx[r];
    f32x4 v = {0.f, 0.f, 0.f, 0.f};
    if (src >= 0) {
      const unsigned short* p = A2 + ((size_t)b * NTOK + src) * 512 + cofs + q4;
      s16x4 hi = *(const s16x4*)&p[0];
#pragma unroll
      for (int j = 0; j < 4; ++j)
        v[j] = bf2f((unsigned short)hi[j]);
    }
    *(f32x4*)&xc[((size_t)b * NTOK + i0 + r) * 256 + q4] = v;
  }
}

// ---------------------------------------------------------------- LayerNorm, z via blockIdx.y
__global__ __launch_bounds__(256) void ln_kernel(
    const float* __restrict__ x, size_t xstr,
    const float* __restrict__ g0, const float* __restrict__ be0,
    const float* __restrict__ g1, const float* __restrict__ be1, int zbase,
    unsigned short* __restrict__ out, size_t ostr, const int* __restrict__ npad)
{
  int z = blockIdx.y;
  x += (size_t)z * xstr; out += (size_t)z * ostr;
  const float* gamma = ((zbase + z) & 1) ? g1 : g0;
  const float* beta  = ((zbase + z) & 1) ? be1 : be0;
  int lane = threadIdx.x & 63, wid = threadIdx.x >> 6;
  int tok = blockIdx.x * 4 + wid;
  int b = tok / NTOK;
  if ((tok - b * NTOK) >= npad[b]) return;
  const float* xp = x + (size_t)tok * 256;
  f32x4 v = *(const f32x4*)&xp[lane * 4];
  float s = v[0] + v[1] + v[2] + v[3];
#pragma unroll
  for (int m = 1; m < 64; m <<= 1) s += __shfl_xor(s, m);
  float mu = s * (1.f / 256.f);
  float vs = 0.f;
#pragma unroll
  for (int j = 0; j < 4; ++j) { float d = v[j] - mu; vs += d * d; }
#pragma unroll
  for (int m = 1; m < 64; m <<= 1) vs += __shfl_xor(vs, m);
  float rs = rsqrtf(vs * (1.f / 256.f) + 1e-5f);
  f32x4 gg = *(const f32x4*)&gamma[lane * 4];
  f32x4 bb = *(const f32x4*)&beta[lane * 4];
  unsigned short r0 = f2bf((v[0] - mu) * rs * gg[0] + bb[0]);
  unsigned short r1 = f2bf((v[1] - mu) * rs * gg[1] + bb[1]);
  unsigned short r2 = f2bf((v[2] - mu) * rs * gg[2] + bb[2]);
  unsigned short r3 = f2bf((v[3] - mu) * rs * gg[3] + bb[3]);
  uint2 pk;
  pk.x = (unsigned)r0 | ((unsigned)r1 << 16);
  pk.y = (unsigned)r2 | ((unsigned)r3 << 16);
  *(uint2*)&out[(size_t)tok * 256 + lane * 4] = pk;
}

// ---------------------------------------------------------------- bf16 GEMM on compact rows, z via blockIdx.z
// EPI: 0=qkv scatter, 1=proj+residual, 2=gelu->bf16, 3=ffn2+residual -> compact refined
template <int EPI>
__global__ __launch_bounds__(256) void gemm_bt(
    const unsigned short* __restrict__ A, size_t astr,
    const unsigned short* __restrict__ Wt, size_t wstr,
    const float* __restrict__ biasA, const float* __restrict__ biasB, int zbase,
    float* __restrict__ xres, size_t xstr,
    float* __restrict__ fout, size_t fstr,
    unsigned short* __restrict__ bout, size_t bstr,
    unsigned short* __restrict__ qb, unsigned short* __restrict__ kb,
    unsigned short* __restrict__ vtb, size_t qstr,
    const int* __restrict__ npad, int N, int K)
{
  int z = blockIdx.z;
  A += (size_t)z * astr;
  Wt += (size_t)z * wstr;
  const float* bias = ((zbase + z) & 1) ? biasB : biasA;
  if (EPI == 0) { qb += (size_t)z * qstr; kb += (size_t)z * qstr; vtb += (size_t)z * qstr; }
  if (EPI == 1 || EPI == 3) xres += (size_t)z * xstr;
  if (EPI == 3) fout += (size_t)z * fstr;
  if (EPI == 2) bout += (size_t)z * bstr;

  int m0 = blockIdx.x * 128, n0 = blockIdx.y * 128;
  int bb = m0 / NTOK;
  if ((m0 - bb * NTOK) >= npad[bb]) return;
  __shared__ unsigned short As[128][72];
  __shared__ unsigned short Ws[128][72];
  int tid = threadIdx.x;
  int lane = tid & 63, wid = tid >> 6;
  int wm = (wid >> 1) * 64, wn = (wid & 1) * 64;
  f32x4 zero = {0.f, 0.f, 0.f, 0.f};
  f32x4 acc[4][4];
#pragma unroll
  for (int i = 0; i < 4; ++i)
#pragma unroll
    for (int j = 0; j < 4; ++j) acc[i][j] = zero;

  for (int kc = 0; kc < K; kc += 64) {
#pragma unroll
    for (int i = 0; i < 4; ++i) {
      int l = tid + i * 256;
      int r = l >> 3, ch = (l & 7) * 8;
      *(short8*)&As[r][ch] = *(const short8*)&A[(size_t)(m0 + r) * K + kc + ch];
      *(short8*)&Ws[r][ch] = *(const short8*)&Wt[(size_t)(n0 + r) * K + kc + ch];
    }
    __syncthreads();
#pragma unroll
    for (int ks = 0; ks < 2; ++ks) {
      short8 a[4], bf[4];
#pragma unroll
      for (int i = 0; i < 4; ++i)
        a[i] = *(const short8*)&As[wm + i * 16 + (lane & 15)][ks * 32 + (lane >> 4) * 8];
#pragma unroll
      for (int j = 0; j < 4; ++j)
        bf[j] = *(const short8*)&Ws[wn + j * 16 + (lane & 15)][ks * 32 + (lane >> 4) * 8];
#pragma unroll
      for (int i = 0; i < 4; ++i)
#pragma unroll
        for (int j = 0; j < 4; ++j)
          acc[i][j] = __builtin_amdgcn_mfma_f32_16x16x32_bf16(a[i], bf[j], acc[i][j], 0, 0, 0);
    }
    __syncthreads();
  }

  int rbase = (lane >> 4) * 4;
  int cbase = lane & 15;
  if (EPI == 0) {
#pragma unroll
    for (int i = 0; i < 4; ++i) {
#pragma unroll
      for (int j = 0; j < 4; ++j) {
        int n = n0 + wn + j * 16 + cbase;
        int sect = n >> 8, hh = (n & 255) >> 6, d = n & 63;
        int mA = m0 + wm + i * 16 + rbase;
        int b = mA / NTOK, tok0 = mA % NTOK;
        size_t bh = (size_t)(b * 4 + hh);
        float vals[4];
#pragma unroll
        for (int r = 0; r < 4; ++r) vals[r] = acc[i][j][r] + bias[n];
        if (sect == 0) {
#pragma unroll
          for (int r = 0; r < 4; ++r)
            qb[(bh * NTOK + tok0 + r) * 64 + d] = f2bf(vals[r] * 0.125f);
        } else if (sect == 1) {
#pragma unroll
          for (int r = 0; r < 4; ++r)
            kb[(bh * NTOK + tok0 + r) * 64 + d] = f2bf(vals[r]);
        } else {
          unsigned short p0 = f2bf(vals[0]), p1 = f2bf(vals[1]);
          unsigned short p2 = f2bf(vals[2]), p3 = f2bf(vals[3]);
          uint2 pk;
          pk.x = (unsigned)p0 | ((unsigned)p1 << 16);
          pk.y = (unsigned)p2 | ((unsigned)p3 << 16);
          *(uint2*)&vtb[(bh * 64 + d) * NTOK + tok0] = pk;
        }
      }
    }
  } else {
#pragma unroll
    for (int i = 0; i < 4; ++i) {
#pragma unroll
      for (int j = 0; j < 4; ++j) {
#pragma unroll
        for (int r = 0; r < 4; ++r) {
          int m = m0 + wm + i * 16 + rbase + r;
          int n = n0 + wn + j * 16 + cbase;
          float v = acc[i][j][r] + bias[n];
          size_t idx = (size_t)m * N + n;
          if (EPI == 1) {
            xres[idx] += v;
          } else if (EPI == 2) {
            float g = 0.5f * v * (1.f + erff(v * 0.70710678118654752f));
            bout[idx] = f2bf(g);
          } else {
            fout[idx] = xres[idx] + v;
          }
        }
      }
    }
  }
}

// ---------------------------------------------------------------- flash attention over compact active keys, z via blockIdx.z
__global__ __launch_bounds__(256) void flash_kernel(
    const unsigned short* __restrict__ Q, const unsigned short* __restrict__ Kt,
    const unsigned short* __restrict__ VT, const int* __restrict__ nact,
    const int* __restrict__ npad, unsigned short* __restrict__ attnout)
{
  int z = blockIdx.z;
  Q += (size_t)z * KVSTR; Kt += (size_t)z * KVSTR; VT += (size_t)z * KVSTR;
  attnout += (size_t)z * BNTC;
  int bh = blockIdx.x, qt = blockIdx.y;
  int b = bh >> 2, h = bh & 3;
  int np = npad[b], na = nact[b];
  if (qt * 64 >= np) return;
  __shared__ unsigned short Ks[64][72];
  __shared__ unsigned short Vs[64][72];
  __shared__ unsigned short Ps[4][16][72];
  __shared__ float madd[64];
  int tid = threadIdx.x, lane = tid & 63, wid = tid >> 6;
  int qrow = qt * 64 + wid * 16 + (lane & 15);
  const unsigned short* qptr = Q + ((size_t)bh * NTOK + qrow) * 64;
  short8 aq0 = *(const short8*)&qptr[(lane >> 4) * 8];
  short8 aq1 = *(const short8*)&qptr[32 + (lane >> 4) * 8];
  f32x4 zero = {0.f, 0.f, 0.f, 0.f};
  f32x4 o[4];
  float mrow[4], lrow[4];
#pragma unroll
  for (int n = 0; n < 4; ++n) o[n] = zero;
#pragma unroll
  for (int r = 0; r < 4; ++r) { mrow[r] = -INFINITY; lrow[r] = 0.f; }
  const unsigned short* kbase = Kt + (size_t)bh * NTOK * 64;
  const unsigned short* vbase = VT + (size_t)bh * 64 * NTOK;
  int nkt = (na + 63) >> 6;

  for (int kt = 0; kt < nkt; ++kt) {
    int k0 = kt * 64;
#pragma unroll
    for (int i = 0; i < 2; ++i) {
      int l = tid + i * 256;
      int r = l >> 3, ch = (l & 7) * 8;
      *(short8*)&Ks[r][ch] = *(const short8*)&kbase[(size_t)(k0 + r) * 64 + ch];
      *(short8*)&Vs[r][ch] = *(const short8*)&vbase[(size_t)r * NTOK + k0 + ch];
    }
    if (tid < 64) madd[tid] = (k0 + tid < na) ? 0.f : -1e9f;
    __syncthreads();

    f32x4 s[4];
#pragma unroll
    for (int n = 0; n < 4; ++n) s[n] = zero;
#pragma unroll
    for (int n = 0; n < 4; ++n) {
      short8 bk0 = *(const short8*)&Ks[n * 16 + (lane & 15)][(lane >> 4) * 8];
      short8 bk1 = *(const short8*)&Ks[n * 16 + (lane & 15)][32 + (lane >> 4) * 8];
      s[n] = __builtin_amdgcn_mfma_f32_16x16x32_bf16(aq0, bk0, s[n], 0, 0, 0);
      s[n] = __builtin_amdgcn_mfma_f32_16x16x32_bf16(aq1, bk1, s[n], 0, 0, 0);
    }
    float pm[4] = {-INFINITY, -INFINITY, -INFINITY, -INFINITY};
#pragma unroll
    for (int n = 0; n < 4; ++n) {
      float ca = madd[n * 16 + (lane & 15)];
#pragma unroll
      for (int r = 0; r < 4; ++r) {
        s[n][r] += ca;
        pm[r] = fmaxf(pm[r], s[n][r]);
      }
    }
#pragma unroll
    for (int r = 0; r < 4; ++r) {
#pragma unroll
      for (int msk = 1; msk < 16; msk <<= 1)
        pm[r] = fmaxf(pm[r], __shfl_xor(pm[r], msk));
    }
    float sf[4], psum[4];
#pragma unroll
    for (int r = 0; r < 4; ++r) {
      float mn = fmaxf(mrow[r], pm[r]);
      sf[r] = __expf(mrow[r] - mn);
      mrow[r] = mn;
      psum[r] = 0.f;
    }
#pragma unroll
    for (int n = 0; n < 4; ++n)
#pragma unroll
      for (int r = 0; r < 4; ++r) {
        float p = __expf(s[n][r] - mrow[r]);
        s[n][r] = p;
        psum[r] += p;
      }
#pragma unroll
    for (int r = 0; r < 4; ++r) {
#pragma unroll
      for (int msk = 1; msk < 16; msk <<= 1)
        psum[r] += __shfl_xor(psum[r], msk);
      lrow[r] = lrow[r] * sf[r] + psum[r];
    }
#pragma unroll
    for (int n = 0; n < 4; ++n)
#pragma unroll
      for (int r = 0; r < 4; ++r) o[n][r] *= sf[r];
#pragma unroll
    for (int n = 0; n < 4; ++n)
#pragma unroll
      for (int r = 0; r < 4; ++r)
        Ps[wid][(lane >> 4) * 4 + r][n * 16 + (lane & 15)] = f2bf(s[n][r]);
    asm volatile("s_waitcnt lgkmcnt(0)" ::: "memory");
    __builtin_amdgcn_sched_barrier(0);
    short8 ap0 = *(const short8*)&Ps[wid][lane & 15][(lane >> 4) * 8];
    short8 ap1 = *(const short8*)&Ps[wid][lane & 15][32 + (lane >> 4) * 8];
#pragma unroll
    for (int n = 0; n < 4; ++n) {
      short8 bv0 = *(const short8*)&Vs[n * 16 + (lane & 15)][(lane >> 4) * 8];
      short8 bv1 = *(const short8*)&Vs[n * 16 + (lane & 15)][32 + (lane >> 4) * 8];
      o[n] = __builtin_amdgcn_mfma_f32_16x16x32_bf16(ap0, bv0, o[n], 0, 0, 0);
      o[n] = __builtin_amdgcn_mfma_f32_16x16x32_bf16(ap1, bv1, o[n], 0, 0, 0);
    }
    __syncthreads();
  }
#pragma unroll
  for (int n = 0; n < 4; ++n)
#pragma unroll
    for (int r = 0; r < 4; ++r) {
      int row = qt * 64 + wid * 16 + (lane >> 4) * 4 + r;
      int col = h * 64 + n * 16 + (lane & 15);
      float v = o[n][r] / lrow[r];
      attnout[((size_t)b * NTOK + row) * 256 + col] = f2bf(v);
    }
}

// ---------------------------------------------------------------- final scatter-back fusion (inverse-map gather)
__global__ __launch_bounds__(256) void final_kernel(
    const float* __restrict__ f_ir, const float* __restrict__ f_vis,
    const float* __restrict__ rirc, const float* __restrict__ rvisc,
    const float* __restrict__ w32, const float* __restrict__ soft,
    const int* __restrict__ invmap, const float* __restrict__ hs_ptr,
    float* __restrict__ out)
{
  __shared__ float tir[64][65], tvis[64][65];
  __shared__ float wl[64], sl[64];
  __shared__ int il[64];
  int n0 = blockIdx.x * 64, c0 = blockIdx.y * 64, b = blockIdx.z;
  int tid = threadIdx.x;
  float hs = hs_ptr[0];
  if (tid < 64) {
    int t = b * NTOK + n0 + tid;
    wl[tid] = w32[t]; sl[tid] = soft[t]; il[tid] = invmap[t];
  }
  __syncthreads();
#pragma unroll
  for (int i = 0; i < 16; ++i) {
    int l = tid + i * 256;
    int r = l >> 6, col = l & 63;
    int ci = il[r];
    if (ci >= 0) {
      size_t idx = ((size_t)b * NTOK + ci) * 256 + c0 + col;
      tir[r][col] = rirc[idx];
      tvis[r][col] = rvisc[idx];
    }
  }
  __syncthreads();
#pragma unroll
  for (int i = 0; i < 16; ++i) {
    int l = tid + i * 256;
    int r = l >> 6, col = l & 63;
    size_t gidx = ((size_t)b * 256 + c0 + r) * NTOK + n0 + col;
    float base = f_ir[gidx] + f_vis[gidx];
    float val;
    if (il[col] >= 0) {
      float ww = wl[col], ss = sl[col];
      float fusion = tir[col][r] * ww + tvis[col][r] * (1.f - ww);
      val = (base + fusion * ss) * (1.f + ss * hs);
    } else {
      val = base;
    }
    out[gidx] = val;
  }
  if (blockIdx.x == 0 && blockIdx.y == 0 && blockIdx.z == 0 && tid == 0)
    out[(size_t)NB * 256 * NTOK] = 0.f;   // aux_loss
}

// ================================================================ host
extern "C" void kernel_launch(void* const* d_in, const int* in_sizes, int n_in,
                              void* d_out, int out_size, void* d_ws, size_t ws_size,
                              hipStream_t stream)
{
  const float* f_ir     = (const float*)d_in[0];
  const float* f_vis    = (const float*)d_in[1];
  const float* agent_w1 = (const float*)d_in[2];
  const float* agent_b1 = (const float*)d_in[3];
  const float* bn_gamma = (const float*)d_in[4];
  const float* bn_beta  = (const float*)d_in[5];
  const float* bn_mean  = (const float*)d_in[6];
  const float* bn_var   = (const float*)d_in[7];
  const float* agent_w2 = (const float*)d_in[8];
  const float* agent_b2 = (const float*)d_in[9];
  const float* hyp_w1   = (const float*)d_in[10];
  const float* hyp_b1   = (const float*)d_in[11];
  const float* hyp_w2   = (const float*)d_in[12];
  const float* hyp_b2   = (const float*)d_in[13];
  int hs_idx = (in_sizes[14] == 1) ? 14 : 34;
  int mix0   = (in_sizes[14] == 1) ? 15 : 14;
  const float* hs_ptr = (const float*)d_in[hs_idx];
  const float* mir_ln_g = (const float*)d_in[mix0 + 0];
  const float* mir_ln_b = (const float*)d_in[mix0 + 1];
  const float* mir_in_w = (const float*)d_in[mix0 + 2];
  const float* mir_in_b = (const float*)d_in[mix0 + 3];
  const float* mir_out_w= (const float*)d_in[mix0 + 4];
  const float* mir_out_b= (const float*)d_in[mix0 + 5];
  const float* mir_f1_w = (const float*)d_in[mix0 + 6];
  const float* mir_f1_b = (const float*)d_in[mix0 + 7];
  const float* mir_f2_w = (const float*)d_in[mix0 + 8];
  const float* mir_f2_b = (const float*)d_in[mix0 + 9];
  const float* mvis_ln_g = (const float*)d_in[mix0 + 10];
  const float* mvis_ln_b = (const float*)d_in[mix0 + 11];
  const float* mvis_in_w = (const float*)d_in[mix0 + 12];
  const float* mvis_in_b = (const float*)d_in[mix0 + 13];
  const float* mvis_out_w= (const float*)d_in[mix0 + 14];
  const float* mvis_out_b= (const float*)d_in[mix0 + 15];
  const float* mvis_f1_w = (const float*)d_in[mix0 + 16];
  const float* mvis_f1_b = (const float*)d_in[mix0 + 17];
  const float* mvis_f2_w = (const float*)d_in[mix0 + 18];
  const float* mvis_f2_b = (const float*)d_in[mix0 + 19];

  auto padded = [](size_t bytes) { return (bytes + 255) & ~(size_t)255; };
  size_t need2 = padded(2 * BNTC * 4)
               + padded(2 * BNTC * 2)
               + 3 * padded(2 * KVSTR * 2)
               + padded(2 * BNTC * 2)
               + padded(2 * BNTC * 4)
               + padded((size_t)2 * 786432 * 2)
               + padded((size_t)512 * 1024 * 2)
               + padded((size_t)BNT * 16 * 4)
               + padded((size_t)BNT * 8)
               + padded(64) + padded(64)
               + 3 * padded((size_t)BNT * 4)
               + padded((size_t)RCAP * 4)
               + 2 * padded((size_t)BNT * 4)
               + 2 * padded(64);
  int zc = (ws_size >= need2 + (1 << 20)) ? 2 : 1;

  char* ws = (char*)d_ws;
  size_t off = 0;
  auto alloc = [&](size_t bytes) {
    size_t o = off;
    off = (off + bytes + 255) & ~(size_t)255;
    return o;
  };
  size_t o_xc    = alloc(2 * BNTC * 4);
  size_t o_xn    = alloc((size_t)zc * BNTC * 2);
  size_t o_q     = alloc((size_t)zc * KVSTR * 2);
  size_t o_k     = alloc((size_t)zc * KVSTR * 2);
  size_t o_vt    = alloc((size_t)zc * KVSTR * 2);
  size_t o_attn  = alloc((size_t)zc * BNTC * 2);
  size_t o_rr    = alloc(2 * BNTC * 4);
  size_t o_wbf   = alloc((size_t)2 * 786432 * 2);
  size_t o_w2s   = alloc((size_t)512 * 1024 * 2);
  size_t o_hp    = alloc((size_t)BNT * 16 * 4);
  size_t o_w64   = alloc((size_t)BNT * 8);
  size_t o_t64   = alloc(64);
  size_t o_count = alloc(64);
  size_t o_w32   = alloc((size_t)BNT * 4);
  size_t o_soft  = alloc((size_t)BNT * 4);
  size_t o_act   = alloc((size_t)BNT * 4);
  size_t o_rlist = alloc((size_t)RCAP * 4);
  size_t o_aidx  = alloc((size_t)BNT * 4);
  size_t o_inv   = alloc((size_t)BNT * 4);
  size_t o_nact  = alloc(64);
  size_t o_npad  = alloc(64);
  (void)n_in; (void)out_size;

  float*  xc   = (float*)(ws + o_xc);
  unsigned short* xn   = (unsigned short*)(ws + o_xn);
  unsigned short* q    = (unsigned short*)(ws + o_q);
  unsigned short* k    = (unsigned short*)(ws + o_k);
  unsigned short* vt   = (unsigned short*)(ws + o_vt);
  unsigned short* attn = (unsigned short*)(ws + o_attn);
  unsigned short* hffn = (unsigned short*)(ws + o_q);
  float*  rr   = (float*)(ws + o_rr);
  unsigned short* A2 = (unsigned short*)(ws + o_rr);   // x_hi [BNT][512]; dead before EPI3 writes
  unsigned short* wbf  = (unsigned short*)(ws + o_wbf);
  unsigned short* W2   = (unsigned short*)(ws + o_w2s);
  float*  hpart = (float*)(ws + o_hp);
  double* w64  = (double*)(ws + o_w64);
  double* t64  = (double*)(ws + o_t64);
  int*    cnt  = (int*)(ws + o_count);
  int*    rcount = cnt + 8;
  float*  w32  = (float*)(ws + o_w32);
  float*  soft = (float*)(ws + o_soft);
  int*    act  = (int*)(ws + o_act);
  int*    rlist = (int*)(ws + o_rlist);
  int*    aidx = (int*)(ws + o_aidx);
  int*    invm = (int*)(ws + o_inv);
  int*    nact = (int*)(ws + o_nact);
  int*    npad = (int*)(ws + o_npad);

  const unsigned short* mir_in  = wbf;
  const unsigned short* mir_out = wbf + 196608;
  const unsigned short* mir_f1  = wbf + 262144;
  const unsigned short* mir_f2  = wbf + 524288;
  const unsigned short* vis_in  = wbf + 786432;
  const unsigned short* vis_out = wbf + 786432 + 196608;
  const unsigned short* vis_f1  = wbf + 786432 + 262144;
  const unsigned short* vis_f2  = wbf + 786432 + 524288;

  // --- independent setup (off the decision chain)
  hipMemsetAsync(cnt, 0, 16 * sizeof(int), stream);
  convert_weights<<<6144, 256, 0, stream>>>(mir_in_w, mir_out_w, mir_f1_w, mir_f2_w,
                                            mvis_in_w, mvis_out_w, mvis_f1_w, mvis_f2_w,
                                            wbf);
  split_w_kernel<<<1024, 256, 0, stream>>>(agent_w1, W2);
  split_x_kernel<<<dim3(36, 8, 8), 256, 0, stream>>>(f_ir, f_vis, A2);

  // --- agent decision chain
  agent_gemm<<<dim3(BNT / 128, 8), 256, 0, stream>>>(
      A2, W2, agent_b1, bn_gamma, bn_beta, bn_mean, bn_var, agent_w2, hpart);
  decide_kernel<<<8, 256, 0, stream>>>(
      hpart, agent_b2, hyp_w1, hyp_b1, hyp_w2, hyp_b2, w64, w32, t64, rcount, rlist);
  refine_kernel<<<RCAP, 256, 0, stream>>>(
      f_ir, f_vis, agent_w1, agent_b1, bn_gamma, bn_beta, bn_mean, bn_var,
      agent_w2, agent_b2, rlist, rcount, w64, w32);
  compact_kernel<<<8, 256, 0, stream>>>(w64, t64, soft, act, aidx, invm, nact, npad);

  // --- gather both compact residual streams (z: 0=ir, 1=vis)
  gather_kernel<<<dim3(36, 8, 2), 256, 0, stream>>>(A2, aidx, npad, xc);

  if (zc == 2) {
    size_t WSTR = 786432;
    ln_kernel<<<dim3(BNT / 4, 2), 256, 0, stream>>>(
        xc, BNTC, mir_ln_g, mir_ln_b, mvis_ln_g, mvis_ln_b, 0, xn, BNTC, npad);
    gemm_bt<0><<<dim3(BNT / 128, 6, 2), 256, 0, stream>>>(
        xn, BNTC, mir_in, WSTR, mir_in_b, mvis_in_b, 0,
        nullptr, 0, nullptr, 0, nullptr, 0, q, k, vt, KVSTR, npad, 768, 256);
    flash_kernel<<<dim3(32, 36, 2), 256, 0, stream>>>(q, k, vt, nact, npad, attn);
    gemm_bt<1><<<dim3(BNT / 128, 2, 2), 256, 0, stream>>>(
        attn, BNTC, mir_out, WSTR, mir_out_b, mvis_out_b, 0,
        xc, BNTC, nullptr, 0, nullptr, 0, nullptr, nullptr, nullptr, 0, npad, 256, 256);
    ln_kernel<<<dim3(BNT / 4, 2), 256, 0, stream>>>(
        xc, BNTC, mir_ln_g, mir_ln_b, mvis_ln_g, mvis_ln_b, 0, xn, BNTC, npad);
    gemm_bt<2><<<dim3(BNT / 128, 8, 2), 256, 0, stream>>>(
        xn, BNTC, mir_f1, WSTR, mir_f1_b, mvis_f1_b, 0,
        nullptr, 0, nullptr, 0, hffn, HSTR, nullptr, nullptr, nullptr, 0, npad, 1024, 256);
    gemm_bt<3><<<dim3(BNT / 128, 2, 2), 256, 0, stream>>>(
        hffn, HSTR, mir_f2, WSTR, mir_f2_b, mvis_f2_b, 0,
        xc, BNTC, rr, BNTC, nullptr, 0, nullptr, nullptr, nullptr, 0, npad, 256, 1024);
  } else {
    for (int s = 0; s < 2; ++s) {
      const float* g   = s ? mvis_ln_g : mir_ln_g;
      const float* be  = s ? mvis_ln_b : mir_ln_b;
      const unsigned short* w_in  = s ? vis_in  : mir_in;
      const unsigned short* w_out = s ? vis_out : mir_out;
      const unsigned short* w_f1  = s ? vis_f1  : mir_f1;
      const unsigned short* w_f2  = s ? vis_f2  : mir_f2;
      const float* b_in  = s ? mvis_in_b  : mir_in_b;
      const float* b_out = s ? mvis_out_b : mir_out_b;
      const float* b_f1  = s ? mvis_f1_b  : mir_f1_b;
      const float* b_f2  = s ? mvis_f2_b  : mir_f2_b;
      float* xcs = xc + (size_t)s * BNTC;
      float* rrs = rr + (size_t)s * BNTC;
      ln_kernel<<<dim3(BNT / 4, 1), 256, 0, stream>>>(
          xcs, 0, g, be, g, be, 0, xn, 0, npad);
      gemm_bt<0><<<dim3(BNT / 128, 6, 1), 256, 0, stream>>>(
          xn, 0, w_in, 0, b_in, b_in, 0,
          nullptr, 0, nullptr, 0, nullptr, 0, q, k, vt, 0, npad, 768, 256);
      flash_kernel<<<dim3(32, 36, 1), 256, 0, stream>>>(q, k, vt, nact, npad, attn);
      gemm_bt<1><<<dim3(BNT / 128, 2, 1), 256, 0, stream>>>(
          attn, 0, w_out, 0, b_out, b_out, 0,
          xcs, 0, nullptr, 0, nullptr, 0, nullptr, nullptr, nullptr, 0, npad, 256, 256);
      ln_kernel<<<dim3(BNT / 4, 1), 256, 0, stream>>>(
          xcs, 0, g, be, g, be, 0, xn, 0, npad);
      gemm_bt<2><<<dim3(BNT / 128, 8, 1), 256, 0, stream>>>(
          xn, 0, w_f1, 0, b_f1, b_f1, 0,
          nullptr, 0, nullptr, 0, hffn, 0, nullptr, nullptr, nullptr, 0, npad, 1024, 256);
      gemm_bt<3><<<dim3(BNT / 128, 2, 1), 256, 0, stream>>>(
          hffn, 0, w_f2, 0, b_f2, b_f2, 0,
          xcs, 0, rrs, 0, nullptr, 0, nullptr, nullptr, nullptr, 0, npad, 256, 1024);
    }
  }

  // --- final fusion + aux loss
  final_kernel<<<dim3(36, 4, 8), 256, 0, stream>>>(
      f_ir, f_vis, rr, rr + BNTC, w32, soft, invm, hs_ptr, (float*)d_out);
}

// Round 12
// 240.276 us; speedup vs baseline: 1.5447x; 1.0503x over previous
//
#include <hip/hip_runtime.h>
#include <hip/hip_bf16.h>
#include <cstdint>
#include <cstddef>

typedef __attribute__((ext_vector_type(8))) short short8;
typedef __attribute__((ext_vector_type(4))) short s16x4;
typedef __attribute__((ext_vector_type(4))) float f32x4;

#define DEVI static __device__ __forceinline__

constexpr int NB   = 8;
constexpr int CDIM = 256;
constexpr int NTOK = 2304;          // 48*48
constexpr int BNT  = NB * NTOK;     // 18432
constexpr int HIDN = 512;
constexpr int RCAP = 4096;          // refine-list capacity
constexpr size_t BNTC = (size_t)BNT * CDIM;          // 4,718,592 elements
constexpr size_t KVSTR = (size_t)32 * NTOK * 64;     // q/k/vt per-z stride (elements)
constexpr size_t HSTR  = (size_t)BNT * 1024;         // hffn per-z stride (elements)

DEVI unsigned short f2bf(float f) {
  unsigned u = __builtin_bit_cast(unsigned, f);
  unsigned r = 0x7FFFu + ((u >> 16) & 1u);
  return (unsigned short)((u + r) >> 16);
}
DEVI float bf2f(unsigned short h) {
  unsigned u = ((unsigned)h) << 16;
  return __builtin_bit_cast(float, u);
}

// ---------------------------------------------------------------- weights->bf16
__global__ __launch_bounds__(256) void convert_weights(
    const float* __restrict__ miw, const float* __restrict__ mow,
    const float* __restrict__ mf1, const float* __restrict__ mf2,
    const float* __restrict__ viw, const float* __restrict__ vow,
    const float* __restrict__ vf1, const float* __restrict__ vf2,
    unsigned short* __restrict__ dst)
{
  int i = blockIdx.x * 256 + threadIdx.x;
  int m = i / 786432;
  int r = i % 786432;
  const float* src; int off;
  if      (r < 196608) { src = m ? viw : miw; off = r; }
  else if (r < 262144) { src = m ? vow : mow; off = r - 196608; }
  else if (r < 524288) { src = m ? vf1 : mf1; off = r - 262144; }
  else                 { src = m ? vf2 : mf2; off = r - 524288; }
  dst[i] = f2bf(src[off]);
}

// ---------------------------------------------------------------- agent W1 -> bf16x2 split [512][1024]
__global__ __launch_bounds__(256) void split_w_kernel(
    const float* __restrict__ w1, unsigned short* __restrict__ W2)
{
  int i = blockIdx.x * 256 + threadIdx.x;
  int n = i >> 9, k = i & 511;
  float v = w1[i];
  unsigned short hi = f2bf(v);
  float r1 = v - bf2f(hi);
  unsigned short mid = f2bf(r1);
  size_t base = (size_t)n * 1024 + k;
  W2[base] = hi; W2[base + 512] = mid;
}

// ---------------------------------------------------------------- x -> bf16 hi plane, pixel-major [BNT][512]
__global__ __launch_bounds__(256) void split_x_kernel(
    const float* __restrict__ f_ir, const float* __restrict__ f_vis,
    unsigned short* __restrict__ A2)
{
  __shared__ float tile[64][65];
  int n0 = blockIdx.x * 64, c0 = blockIdx.y * 64, b = blockIdx.z;
  int tid = threadIdx.x;
  const float* src = (c0 < 256) ? f_ir : f_vis;
  int cc0 = c0 & 255;
#pragma unroll
  for (int i = 0; i < 16; ++i) {
    int l = tid + i * 256;
    int r = l >> 6, col = l & 63;
    tile[r][col] = src[((size_t)b * 256 + cc0 + r) * NTOK + n0 + col];
  }
  __syncthreads();
#pragma unroll
  for (int i = 0; i < 16; ++i) {
    int l = tid + i * 256;
    int r = l >> 6, col = l & 63;
    A2[((size_t)b * NTOK + n0 + r) * 512 + c0 + col] = f2bf(tile[col][r]);
  }
}

// ---------------------------------------------------------------- agent GEMM (128x64) single-pass x_hi x (W_hi|W_mid) + fused epilogue
__global__ __launch_bounds__(256) void agent_gemm(
    const unsigned short* __restrict__ A2, const unsigned short* __restrict__ W2,
    const float* __restrict__ b1,
    const float* __restrict__ bng, const float* __restrict__ bnb,
    const float* __restrict__ bnm, const float* __restrict__ bnv,
    const float* __restrict__ w2, float* __restrict__ hpart)
{
  __shared__ unsigned short As[128][72];
  __shared__ unsigned short Ws[128][72];   // rows 0-63: W-hi, rows 64-127: W-mid
  __shared__ float scl[64], shl[64], w2l[64];
  int tid = threadIdx.x;
  int lane = tid & 63, wid = tid >> 6;
  int wm = (wid >> 1) * 64, wn = (wid & 1) * 32;
  int m0 = blockIdx.x * 128, n0 = blockIdx.y * 64;
  if (tid < 64) {
    int n = n0 + tid;
    double inv = 1.0 / sqrt((double)bnv[n] + 1e-5);
    double sc = (double)bng[n] * inv;
    scl[tid] = (float)sc;
    shl[tid] = (float)(((double)b1[n] - (double)bnm[n]) * sc + (double)bnb[n]);
    w2l[tid] = w2[n];
  }
  f32x4 zero = {0.f, 0.f, 0.f, 0.f};
  f32x4 acc[4][2];
#pragma unroll
  for (int i = 0; i < 4; ++i)
#pragma unroll
    for (int j = 0; j < 2; ++j) acc[i][j] = zero;

  for (int kin = 0; kin < 512; kin += 64) {
    __syncthreads();
#pragma unroll
    for (int i = 0; i < 4; ++i) {
      int l = tid + i * 256;
      int r = l >> 3, ch = (l & 7) * 8;
      *(short8*)&As[r][ch] = *(const short8*)&A2[(size_t)(m0 + r) * 512 + kin + ch];
    }
#pragma unroll
    for (int i = 0; i < 4; ++i) {
      int l = tid + i * 256;
      int r = l >> 3, ch = (l & 7) * 8;
      int wr = (r < 64) ? r : (r - 64);
      int wo = (r < 64) ? 0 : 512;
      *(short8*)&Ws[r][ch] = *(const short8*)&W2[(size_t)(n0 + wr) * 1024 + wo + kin + ch];
    }
    __syncthreads();
#pragma unroll
    for (int ks = 0; ks < 2; ++ks) {
      short8 a[4], bh[2], bm[2];
#pragma unroll
      for (int i = 0; i < 4; ++i)
        a[i] = *(const short8*)&As[wm + i * 16 + (lane & 15)][ks * 32 + (lane >> 4) * 8];
#pragma unroll
      for (int j = 0; j < 2; ++j) {
        bh[j] = *(const short8*)&Ws[wn + j * 16 + (lane & 15)][ks * 32 + (lane >> 4) * 8];
        bm[j] = *(const short8*)&Ws[64 + wn + j * 16 + (lane & 15)][ks * 32 + (lane >> 4) * 8];
      }
#pragma unroll
      for (int i = 0; i < 4; ++i)
#pragma unroll
        for (int j = 0; j < 2; ++j) {
          acc[i][j] = __builtin_amdgcn_mfma_f32_16x16x32_bf16(a[i], bh[j], acc[i][j], 0, 0, 0);
          acc[i][j] = __builtin_amdgcn_mfma_f32_16x16x32_bf16(a[i], bm[j], acc[i][j], 0, 0, 0);
        }
    }
  }

  int rbase = (lane >> 4) * 4;
  int cbase = lane & 15;
  float part[4][4];
#pragma unroll
  for (int i = 0; i < 4; ++i) {
#pragma unroll
    for (int r = 0; r < 4; ++r) {
      float p = 0.f;
#pragma unroll
      for (int j = 0; j < 2; ++j) {
        int nl = wn + j * 16 + cbase;
        float val = acc[i][j][r] * scl[nl] + shl[nl];
        if (val > 0.f) p += val * w2l[nl];
      }
      part[i][r] = p;
    }
  }
#pragma unroll
  for (int msk = 1; msk < 16; msk <<= 1) {
#pragma unroll
    for (int i = 0; i < 4; ++i)
#pragma unroll
      for (int r = 0; r < 4; ++r)
        part[i][r] += __shfl_xor(part[i][r], msk);
  }
  if (cbase == 0) {
    int slot = blockIdx.y * 2 + (wid & 1);
#pragma unroll
    for (int i = 0; i < 4; ++i)
#pragma unroll
      for (int r = 0; r < 4; ++r) {
        int mm = m0 + wm + i * 16 + rbase + r;
        hpart[(size_t)mm * 16 + slot] = part[i][r];
      }
  }
}

// ---------------------------------------------------------------- decide: partials -> w (sigmoid), mean -> t, flag window (wave-agg)
__global__ __launch_bounds__(256) void decide_kernel(
    const float* __restrict__ hpart, const float* __restrict__ b2,
    const float* __restrict__ hw1, const float* __restrict__ hb1,
    const float* __restrict__ hw2, const float* __restrict__ hb2,
    double* __restrict__ w64, float* __restrict__ w32, double* __restrict__ t64,
    int* __restrict__ rcount, int* __restrict__ rlist)
{
  __shared__ double red[256];
  __shared__ double tsh;
  int b = blockIdx.x, tid = threadIdx.x, lane = tid & 63;
  unsigned long long ltmask = (1ull << lane) - 1ull;
  double wloc[9];
  double s = 0.0;
#pragma unroll
  for (int c = 0; c < 9; ++c) {
    int pix = b * NTOK + c * 256 + tid;
    const float* hp = hpart + (size_t)pix * 16;
    double lg = (double)b2[0];
#pragma unroll
    for (int j = 0; j < 16; ++j) lg += (double)hp[j];
    double wd = 1.0 / (1.0 + exp(-lg));
    w64[pix] = wd; w32[pix] = (float)wd;
    wloc[c] = wd;
    s += wd;
  }
  red[tid] = s;
  __syncthreads();
  for (int st = 128; st; st >>= 1) {
    if (tid < st) red[tid] += red[tid + st];
    __syncthreads();
  }
  if (tid == 0) {
    double g = red[0] / 2304.0;
    double acc = (double)hb2[0];
    for (int j = 0; j < 16; ++j) {
      double hh = g * (double)hw1[j] + (double)hb1[j];
      hh = hh > 0.0 ? hh : 0.0;
      acc += hh * (double)hw2[j];
    }
    tsh = 1.0 / (1.0 + exp(-acc));
    t64[b] = tsh;
  }
  __syncthreads();
  double t = tsh;
#pragma unroll
  for (int c = 0; c < 9; ++c) {
    int flag = fabs(wloc[c] - t) < 4e-4 ? 1 : 0;
    unsigned long long ball = __ballot(flag);
    if (ball) {
      int leader = __ffsll((long long)ball) - 1;
      int base = 0;
      if (lane == leader) base = atomicAdd(rcount, __popcll(ball));
      base = __shfl(base, leader);
      if (flag) {
        int idx = base + __popcll(ball & ltmask);
        if (idx < RCAP) rlist[idx] = b * NTOK + c * 256 + tid;
      }
    }
  }
}

// ---------------------------------------------------------------- fp64 recompute of flagged pixels (1 pixel/block, 16 waves, 8-way ILP)
__global__ __launch_bounds__(1024) void refine_kernel(
    const float* __restrict__ f_ir, const float* __restrict__ f_vis,
    const float* __restrict__ w1, const float* __restrict__ b1,
    const float* __restrict__ bng, const float* __restrict__ bnb,
    const float* __restrict__ bnm, const float* __restrict__ bnv,
    const float* __restrict__ w2, const float* __restrict__ b2,
    const int* __restrict__ rlist, const int* __restrict__ rcount,
    double* __restrict__ w64, float* __restrict__ w32)
{
  int nr = rcount[0]; if (nr > RCAP) nr = RCAP;
  if ((int)blockIdx.x >= nr) return;
  int pix = rlist[blockIdx.x];
  int b = pix / NTOK, n = pix % NTOK;
  __shared__ double xs[512];
  __shared__ double scs[512], shs[512];
  __shared__ double lred[16];
  int tid = threadIdx.x, lane = tid & 63, wid = tid >> 6;   // 16 waves
  if (tid < 512) {
    const float* fsrc = (tid < 256) ? f_ir : f_vis;
    xs[tid] = (double)fsrc[((size_t)b * 256 + (tid & 255)) * NTOK + n];
    double inv = 1.0 / sqrt((double)bnv[tid] + 1e-5);
    double sc = (double)bng[tid] * inv;
    scs[tid] = sc;
    shs[tid] = ((double)b1[tid] - (double)bnm[tid]) * sc + (double)bnb[tid];
  }
  __syncthreads();
  double xp[8];
#pragma unroll
  for (int j = 0; j < 8; ++j) xp[j] = xs[lane * 8 + j];
  double lg = 0.0;
  for (int oo = 0; oo < 32; oo += 8) {            // each wave owns 32 outputs
    int o = wid * 32 + oo;
    double s[8] = {0, 0, 0, 0, 0, 0, 0, 0};
    const float* wr = w1 + (size_t)o * 512 + lane * 8;
#pragma unroll
    for (int t = 0; t < 8; ++t) {
#pragma unroll
      for (int j = 0; j < 8; ++j)
        s[t] += (double)wr[t * 512 + j] * xp[j];
    }
#pragma unroll
    for (int m = 1; m < 64; m <<= 1) {
#pragma unroll
      for (int t = 0; t < 8; ++t) s[t] += __shfl_xor(s[t], m);
    }
#pragma unroll
    for (int t = 0; t < 8; ++t) {
      int ot = o + t;
      double hv = s[t] * scs[ot] + shs[ot];
      if (hv > 0.0) lg += hv * (double)w2[ot];
    }
  }
  if (lane == 0) lred[wid] = lg;
  __syncthreads();
  if (tid == 0) {
    double L = (double)b2[0];
#pragma unroll
    for (int w = 0; w < 16; ++w) L += lred[w];
    double wd = 1.0 / (1.0 + exp(-L));
    w64[pix] = wd;
    w32[pix] = (float)wd;
  }
}

// ---------------------------------------------------------------- compaction (mask+soft fused, top-64 fallback) + inverse map
__global__ __launch_bounds__(256) void compact_kernel(
    const double* __restrict__ w64, const double* __restrict__ t64,
    float* __restrict__ soft, int* __restrict__ active, int* __restrict__ actidx,
    int* __restrict__ invmap, int* __restrict__ nact, int* __restrict__ npad)
{
  __shared__ double wv[NTOK];
  __shared__ double rv[256];
  __shared__ int   ri[256];
  __shared__ int wtot[9][4];
  int b = blockIdx.x, tid = threadIdx.x, lane = tid & 63, wid = tid >> 6;
  double t = t64[b];
  unsigned long long ltmask = (1ull << lane) - 1ull;

  int sbase = 0;
  for (int c = 0; c < 9; ++c) {
    int i = c * 256 + tid;
    double wd = w64[(size_t)b * NTOK + i];
    double sd = 1.0 / (1.0 + exp(-(wd - t) * 50.0));
    soft[(size_t)b * NTOK + i] = (float)sd;
    int a = sd > 0.5 ? 1 : 0;
    active[(size_t)b * NTOK + i] = a;
    unsigned long long ball = __ballot(a);
    int wpre = __popcll(ball & ltmask);
    if (lane == 0) wtot[c][wid] = __popcll(ball);
    __syncthreads();
    int cross = 0;
    for (int w = 0; w < wid; ++w) cross += wtot[c][w];
    int slot = sbase + cross + wpre;
    if (a) actidx[(size_t)b * NTOK + slot] = i;
    invmap[(size_t)b * NTOK + i] = a ? slot : -1;
    sbase += wtot[c][0] + wtot[c][1] + wtot[c][2] + wtot[c][3];
  }

  if (sbase < 64) {
    for (int i = tid; i < NTOK; i += 256) {
      wv[i] = w64[(size_t)b * NTOK + i];
      active[(size_t)b * NTOK + i] = 0;
    }
    __syncthreads();
    for (int it = 0; it < 64; ++it) {
      double best = -1e300; int bi = 1 << 30;
      for (int i = tid; i < NTOK; i += 256) {
        double vvv = wv[i];
        if (vvv > best || (vvv == best && i < bi)) { best = vvv; bi = i; }
      }
      rv[tid] = best; ri[tid] = bi;
      __syncthreads();
      for (int st = 128; st; st >>= 1) {
        if (tid < st) {
          if (rv[tid + st] > rv[tid] ||
              (rv[tid + st] == rv[tid] && ri[tid + st] < ri[tid])) {
            rv[tid] = rv[tid + st]; ri[tid] = ri[tid + st];
          }
        }
        __syncthreads();
      }
      if (tid == 0) { active[(size_t)b * NTOK + ri[0]] = 1; wv[ri[0]] = -1e300; }
      __syncthreads();
    }
    sbase = 0;
    for (int c = 0; c < 9; ++c) {
      int i = c * 256 + tid;
      int a = active[(size_t)b * NTOK + i];
      unsigned long long ball = __ballot(a);
      int wpre = __popcll(ball & ltmask);
      if (lane == 0) wtot[c][wid] = __popcll(ball);
      __syncthreads();
      int cross = 0;
      for (int w = 0; w < wid; ++w) cross += wtot[c][w];
      int slot = sbase + cross + wpre;
      if (a) actidx[(size_t)b * NTOK + slot] = i;
      invmap[(size_t)b * NTOK + i] = a ? slot : -1;
      sbase += wtot[c][0] + wtot[c][1] + wtot[c][2] + wtot[c][3];
    }
  }
  int n = sbase;
  int np = (n + 127) & ~127;
  if (np > NTOK) np = NTOK;
  for (int i = n + tid; i < np; i += 256) actidx[(size_t)b * NTOK + i] = -1;
  if (tid == 0) { nact[b] = n; npad[b] = np; }
}

// ---------------------------------------------------------------- gather compact rows from x_hi (bf16 -> f32); z = ir/vis
__global__ __launch_bounds__(256) void gather_kernel(
    const unsigned short* __restrict__ A2, const int* __restrict__ actidx,
    const int* __restrict__ npad, float* __restrict__ xc)
{
  int b = blockIdx.y, i0 = blockIdx.x * 64, z = blockIdx.z;
  int cofs = z * 256;
  xc += (size_t)z * BNTC;
  if (i0 >= npad[b]) return;
  __shared__ int idx[64];
  int tid = threadIdx.x;
  if (tid < 64) idx[tid] = actidx[(size_t)b * NTOK + i0 + tid];
  __syncthreads();
#pragma unroll
  for (int it = 0; it < 16; ++it) {
    int s = tid + it * 256;
    int r = s >> 6, q4 = (s & 63) * 4;
    int src = idx[r];
    f32x4 v = {0.f, 0.f, 0.f, 0.f};
    if (src >= 0) {
      const unsigned short* p = A2 + ((size_t)b * NTOK + src) * 512 + cofs + q4;
      s16x4 hi = *(const s16x4*)&p[0];
#pragma unroll
      for (int j = 0; j < 4; ++j)
        v[j] = bf2f((unsigned short)hi[j]);
    }
    *(f32x4*)&xc[((size_t)b * NTOK + i0 + r) * 256 + q4] = v;
  }
}

// ---------------------------------------------------------------- LayerNorm, z via blockIdx.y
__global__ __launch_bounds__(256) void ln_kernel(
    const float* __restrict__ x, size_t xstr,
    const float* __restrict__ g0, const float* __restrict__ be0,
    const float* __restrict__ g1, const float* __restrict__ be1, int zbase,
    unsigned short* __restrict__ out, size_t ostr, const int* __restrict__ npad)
{
  int z = blockIdx.y;
  x += (size_t)z * xstr; out += (size_t)z * ostr;
  const float* gamma = ((zbase + z) & 1) ? g1 : g0;
  const float* beta  = ((zbase + z) & 1) ? be1 : be0;
  int lane = threadIdx.x & 63, wid = threadIdx.x >> 6;
  int tok = blockIdx.x * 4 + wid;
  int b = tok / NTOK;
  if ((tok - b * NTOK) >= npad[b]) return;
  const float* xp = x + (size_t)tok * 256;
  f32x4 v = *(const f32x4*)&xp[lane * 4];
  float s = v[0] + v[1] + v[2] + v[3];
#pragma unroll
  for (int m = 1; m < 64; m <<= 1) s += __shfl_xor(s, m);
  float mu = s * (1.f / 256.f);
  float vs = 0.f;
#pragma unroll
  for (int j = 0; j < 4; ++j) { float d = v[j] - mu; vs += d * d; }
#pragma unroll
  for (int m = 1; m < 64; m <<= 1) vs += __shfl_xor(vs, m);
  float rs = rsqrtf(vs * (1.f / 256.f) + 1e-5f);
  f32x4 gg = *(const f32x4*)&gamma[lane * 4];
  f32x4 bb = *(const f32x4*)&beta[lane * 4];
  unsigned short r0 = f2bf((v[0] - mu) * rs * gg[0] + bb[0]);
  unsigned short r1 = f2bf((v[1] - mu) * rs * gg[1] + bb[1]);
  unsigned short r2 = f2bf((v[2] - mu) * rs * gg[2] + bb[2]);
  unsigned short r3 = f2bf((v[3] - mu) * rs * gg[3] + bb[3]);
  uint2 pk;
  pk.x = (unsigned)r0 | ((unsigned)r1 << 16);
  pk.y = (unsigned)r2 | ((unsigned)r3 << 16);
  *(uint2*)&out[(size_t)tok * 256 + lane * 4] = pk;
}

// ---------------------------------------------------------------- bf16 GEMM on compact rows, z via blockIdx.z
// EPI: 0=qkv scatter, 1=proj+residual, 2=gelu->bf16, 3=ffn2+residual -> compact refined
template <int EPI>
__global__ __launch_bounds__(256) void gemm_bt(
    const unsigned short* __restrict__ A, size_t astr,
    const unsigned short* __restrict__ Wt, size_t wstr,
    const float* __restrict__ biasA, const float* __restrict__ biasB, int zbase,
    float* __restrict__ xres, size_t xstr,
    float* __restrict__ fout, size_t fstr,
    unsigned short* __restrict__ bout, size_t bstr,
    unsigned short* __restrict__ qb, unsigned short* __restrict__ kb,
    unsigned short* __restrict__ vtb, size_t qstr,
    const int* __restrict__ npad, int N, int K)
{
  int z = blockIdx.z;
  A += (size_t)z * astr;
  Wt += (size_t)z * wstr;
  const float* bias = ((zbase + z) & 1) ? biasB : biasA;
  if (EPI == 0) { qb += (size_t)z * qstr; kb += (size_t)z * qstr; vtb += (size_t)z * qstr; }
  if (EPI == 1 || EPI == 3) xres += (size_t)z * xstr;
  if (EPI == 3) fout += (size_t)z * fstr;
  if (EPI == 2) bout += (size_t)z * bstr;

  int m0 = blockIdx.x * 128, n0 = blockIdx.y * 128;
  int bb = m0 / NTOK;
  if ((m0 - bb * NTOK) >= npad[bb]) return;
  __shared__ unsigned short As[128][72];
  __shared__ unsigned short Ws[128][72];
  int tid = threadIdx.x;
  int lane = tid & 63, wid = tid >> 6;
  int wm = (wid >> 1) * 64, wn = (wid & 1) * 64;
  f32x4 zero = {0.f, 0.f, 0.f, 0.f};
  f32x4 acc[4][4];
#pragma unroll
  for (int i = 0; i < 4; ++i)
#pragma unroll
    for (int j = 0; j < 4; ++j) acc[i][j] = zero;

  for (int kc = 0; kc < K; kc += 64) {
#pragma unroll
    for (int i = 0; i < 4; ++i) {
      int l = tid + i * 256;
      int r = l >> 3, ch = (l & 7) * 8;
      *(short8*)&As[r][ch] = *(const short8*)&A[(size_t)(m0 + r) * K + kc + ch];
      *(short8*)&Ws[r][ch] = *(const short8*)&Wt[(size_t)(n0 + r) * K + kc + ch];
    }
    __syncthreads();
#pragma unroll
    for (int ks = 0; ks < 2; ++ks) {
      short8 a[4], bf[4];
#pragma unroll
      for (int i = 0; i < 4; ++i)
        a[i] = *(const short8*)&As[wm + i * 16 + (lane & 15)][ks * 32 + (lane >> 4) * 8];
#pragma unroll
      for (int j = 0; j < 4; ++j)
        bf[j] = *(const short8*)&Ws[wn + j * 16 + (lane & 15)][ks * 32 + (lane >> 4) * 8];
#pragma unroll
      for (int i = 0; i < 4; ++i)
#pragma unroll
        for (int j = 0; j < 4; ++j)
          acc[i][j] = __builtin_amdgcn_mfma_f32_16x16x32_bf16(a[i], bf[j], acc[i][j], 0, 0, 0);
    }
    __syncthreads();
  }

  int rbase = (lane >> 4) * 4;
  int cbase = lane & 15;
  if (EPI == 0) {
#pragma unroll
    for (int i = 0; i < 4; ++i) {
#pragma unroll
      for (int j = 0; j < 4; ++j) {
        int n = n0 + wn + j * 16 + cbase;
        int sect = n >> 8, hh = (n & 255) >> 6, d = n & 63;
        int mA = m0 + wm + i * 16 + rbase;
        int b = mA / NTOK, tok0 = mA % NTOK;
        size_t bh = (size_t)(b * 4 + hh);
        float vals[4];
#pragma unroll
        for (int r = 0; r < 4; ++r) vals[r] = acc[i][j][r] + bias[n];
        if (sect == 0) {
#pragma unroll
          for (int r = 0; r < 4; ++r)
            qb[(bh * NTOK + tok0 + r) * 64 + d] = f2bf(vals[r] * 0.125f);
        } else if (sect == 1) {
#pragma unroll
          for (int r = 0; r < 4; ++r)
            kb[(bh * NTOK + tok0 + r) * 64 + d] = f2bf(vals[r]);
        } else {
          unsigned short p0 = f2bf(vals[0]), p1 = f2bf(vals[1]);
          unsigned short p2 = f2bf(vals[2]), p3 = f2bf(vals[3]);
          uint2 pk;
          pk.x = (unsigned)p0 | ((unsigned)p1 << 16);
          pk.y = (unsigned)p2 | ((unsigned)p3 << 16);
          *(uint2*)&vtb[(bh * 64 + d) * NTOK + tok0] = pk;
        }
      }
    }
  } else {
#pragma unroll
    for (int i = 0; i < 4; ++i) {
#pragma unroll
      for (int j = 0; j < 4; ++j) {
#pragma unroll
        for (int r = 0; r < 4; ++r) {
          int m = m0 + wm + i * 16 + rbase + r;
          int n = n0 + wn + j * 16 + cbase;
          float v = acc[i][j][r] + bias[n];
          size_t idx = (size_t)m * N + n;
          if (EPI == 1) {
            xres[idx] += v;
          } else if (EPI == 2) {
            float g = 0.5f * v * (1.f + erff(v * 0.70710678118654752f));
            bout[idx] = f2bf(g);
          } else {
            fout[idx] = xres[idx] + v;
          }
        }
      }
    }
  }
}

// ---------------------------------------------------------------- flash attention over compact active keys, z via blockIdx.z
__global__ __launch_bounds__(256) void flash_kernel(
    const unsigned short* __restrict__ Q, const unsigned short* __restrict__ Kt,
    const unsigned short* __restrict__ VT, const int* __restrict__ nact,
    const int* __restrict__ npad, unsigned short* __restrict__ attnout)
{
  int z = blockIdx.z;
  Q += (size_t)z * KVSTR; Kt += (size_t)z * KVSTR; VT += (size_t)z * KVSTR;
  attnout += (size_t)z * BNTC;
  int bh = blockIdx.x, qt = blockIdx.y;
  int b = bh >> 2, h = bh & 3;
  int np = npad[b], na = nact[b];
  if (qt * 64 >= np) return;
  __shared__ unsigned short Ks[64][72];
  __shared__ unsigned short Vs[64][72];
  __shared__ unsigned short Ps[4][16][72];
  __shared__ float madd[64];
  int tid = threadIdx.x, lane = tid & 63, wid = tid >> 6;
  int qrow = qt * 64 + wid * 16 + (lane & 15);
  const unsigned short* qptr = Q + ((size_t)bh * NTOK + qrow) * 64;
  short8 aq0 = *(const short8*)&qptr[(lane >> 4) * 8];
  short8 aq1 = *(const short8*)&qptr[32 + (lane >> 4) * 8];
  f32x4 zero = {0.f, 0.f, 0.f, 0.f};
  f32x4 o[4];
  float mrow[4], lrow[4];
#pragma unroll
  for (int n = 0; n < 4; ++n) o[n] = zero;
#pragma unroll
  for (int r = 0; r < 4; ++r) { mrow[r] = -INFINITY; lrow[r] = 0.f; }
  const unsigned short* kbase = Kt + (size_t)bh * NTOK * 64;
  const unsigned short* vbase = VT + (size_t)bh * 64 * NTOK;
  int nkt = (na + 63) >> 6;

  for (int kt = 0; kt < nkt; ++kt) {
    int k0 = kt * 64;
#pragma unroll
    for (int i = 0; i < 2; ++i) {
      int l = tid + i * 256;
      int r = l >> 3, ch = (l & 7) * 8;
      *(short8*)&Ks[r][ch] = *(const short8*)&kbase[(size_t)(k0 + r) * 64 + ch];
      *(short8*)&Vs[r][ch] = *(const short8*)&vbase[(size_t)r * NTOK + k0 + ch];
    }
    if (tid < 64) madd[tid] = (k0 + tid < na) ? 0.f : -1e9f;
    __syncthreads();

    f32x4 s[4];
#pragma unroll
    for (int n = 0; n < 4; ++n) s[n] = zero;
#pragma unroll
    for (int n = 0; n < 4; ++n) {
      short8 bk0 = *(const short8*)&Ks[n * 16 + (lane & 15)][(lane >> 4) * 8];
      short8 bk1 = *(const short8*)&Ks[n * 16 + (lane & 15)][32 + (lane >> 4) * 8];
      s[n] = __builtin_amdgcn_mfma_f32_16x16x32_bf16(aq0, bk0, s[n], 0, 0, 0);
      s[n] = __builtin_amdgcn_mfma_f32_16x16x32_bf16(aq1, bk1, s[n], 0, 0, 0);
    }
    float pm[4] = {-INFINITY, -INFINITY, -INFINITY, -INFINITY};
#pragma unroll
    for (int n = 0; n < 4; ++n) {
      float ca = madd[n * 16 + (lane & 15)];
#pragma unroll
      for (int r = 0; r < 4; ++r) {
        s[n][r] += ca;
        pm[r] = fmaxf(pm[r], s[n][r]);
      }
    }
#pragma unroll
    for (int r = 0; r < 4; ++r) {
#pragma unroll
      for (int msk = 1; msk < 16; msk <<= 1)
        pm[r] = fmaxf(pm[r], __shfl_xor(pm[r], msk));
    }
    float sf[4], psum[4];
#pragma unroll
    for (int r = 0; r < 4; ++r) {
      float mn = fmaxf(mrow[r], pm[r]);
      sf[r] = __expf(mrow[r] - mn);
      mrow[r] = mn;
      psum[r] = 0.f;
    }
#pragma unroll
    for (int n = 0; n < 4; ++n)
#pragma unroll
      for (int r = 0; r < 4; ++r) {
        float p = __expf(s[n][r] - mrow[r]);
        s[n][r] = p;
        psum[r] += p;
      }
#pragma unroll
    for (int r = 0; r < 4; ++r) {
#pragma unroll
      for (int msk = 1; msk < 16; msk <<= 1)
        psum[r] += __shfl_xor(psum[r], msk);
      lrow[r] = lrow[r] * sf[r] + psum[r];
    }
#pragma unroll
    for (int n = 0; n < 4; ++n)
#pragma unroll
      for (int r = 0; r < 4; ++r) o[n][r] *= sf[r];
#pragma unroll
    for (int n = 0; n < 4; ++n)
#pragma unroll
      for (int r = 0; r < 4; ++r)
        Ps[wid][(lane >> 4) * 4 + r][n * 16 + (lane & 15)] = f2bf(s[n][r]);
    asm volatile("s_waitcnt lgkmcnt(0)" ::: "memory");
    __builtin_amdgcn_sched_barrier(0);
    short8 ap0 = *(const short8*)&Ps[wid][lane & 15][(lane >> 4) * 8];
    short8 ap1 = *(const short8*)&Ps[wid][lane & 15][32 + (lane >> 4) * 8];
#pragma unroll
    for (int n = 0; n < 4; ++n) {
      short8 bv0 = *(const short8*)&Vs[n * 16 + (lane & 15)][(lane >> 4) * 8];
      short8 bv1 = *(const short8*)&Vs[n * 16 + (lane & 15)][32 + (lane >> 4) * 8];
      o[n] = __builtin_amdgcn_mfma_f32_16x16x32_bf16(ap0, bv0, o[n], 0, 0, 0);
      o[n] = __builtin_amdgcn_mfma_f32_16x16x32_bf16(ap1, bv1, o[n], 0, 0, 0);
    }
    __syncthreads();
  }
#pragma unroll
  for (int n = 0; n < 4; ++n)
#pragma unroll
    for (int r = 0; r < 4; ++r) {
      int row = qt * 64 + wid * 16 + (lane >> 4) * 4 + r;
      int col = h * 64 + n * 16 + (lane & 15);
      float v = o[n][r] / lrow[r];
      attnout[((size_t)b * NTOK + row) * 256 + col] = f2bf(v);
    }
}

// ---------------------------------------------------------------- final scatter-back fusion (inverse-map gather)
__global__ __launch_bounds__(256) void final_kernel(
    const float* __restrict__ f_ir, const float* __restrict__ f_vis,
    const float* __restrict__ rirc, const float* __restrict__ rvisc,
    const float* __restrict__ w32, const float* __restrict__ soft,
    const int* __restrict__ invmap, const float* __restrict__ hs_ptr,
    float* __restrict__ out)
{
  __shared__ float tir[64][65], tvis[64][65];
  __shared__ float wl[64], sl[64];
  __shared__ int il[64];
  int n0 = blockIdx.x * 64, c0 = blockIdx.y * 64, b = blockIdx.z;
  int tid = threadIdx.x;
  float hs = hs_ptr[0];
  if (tid < 64) {
    int t = b * NTOK + n0 + tid;
    wl[tid] = w32[t]; sl[tid] = soft[t]; il[tid] = invmap[t];
  }
  __syncthreads();
#pragma unroll
  for (int i = 0; i < 16; ++i) {
    int l = tid + i * 256;
    int r = l >> 6, col = l & 63;
    int ci = il[r];
    if (ci >= 0) {
      size_t idx = ((size_t)b * NTOK + ci) * 256 + c0 + col;
      tir[r][col] = rirc[idx];
      tvis[r][col] = rvisc[idx];
    }
  }
  __syncthreads();
#pragma unroll
  for (int i = 0; i < 16; ++i) {
    int l = tid + i * 256;
    int r = l >> 6, col = l & 63;
    size_t gidx = ((size_t)b * 256 + c0 + r) * NTOK + n0 + col;
    float base = f_ir[gidx] + f_vis[gidx];
    float val;
    if (il[col] >= 0) {
      float ww = wl[col], ss = sl[col];
      float fusion = tir[col][r] * ww + tvis[col][r] * (1.f - ww);
      val = (base + fusion * ss) * (1.f + ss * hs);
    } else {
      val = base;
    }
    out[gidx] = val;
  }
  if (blockIdx.x == 0 && blockIdx.y == 0 && blockIdx.z == 0 && tid == 0)
    out[(size_t)NB * 256 * NTOK] = 0.f;   // aux_loss
}

// ================================================================ host
extern "C" void kernel_launch(void* const* d_in, const int* in_sizes, int n_in,
                              void* d_out, int out_size, void* d_ws, size_t ws_size,
                              hipStream_t stream)
{
  const float* f_ir     = (const float*)d_in[0];
  const float* f_vis    = (const float*)d_in[1];
  const float* agent_w1 = (const float*)d_in[2];
  const float* agent_b1 = (const float*)d_in[3];
  const float* bn_gamma = (const float*)d_in[4];
  const float* bn_beta  = (const float*)d_in[5];
  const float* bn_mean  = (const float*)d_in[6];
  const float* bn_var   = (const float*)d_in[7];
  const float* agent_w2 = (const float*)d_in[8];
  const float* agent_b2 = (const float*)d_in[9];
  const float* hyp_w1   = (const float*)d_in[10];
  const float* hyp_b1   = (const float*)d_in[11];
  const float* hyp_w2   = (const float*)d_in[12];
  const float* hyp_b2   = (const float*)d_in[13];
  int hs_idx = (in_sizes[14] == 1) ? 14 : 34;
  int mix0   = (in_sizes[14] == 1) ? 15 : 14;
  const float* hs_ptr = (const float*)d_in[hs_idx];
  const float* mir_ln_g = (const float*)d_in[mix0 + 0];
  const float* mir_ln_b = (const float*)d_in[mix0 + 1];
  const float* mir_in_w = (const float*)d_in[mix0 + 2];
  const float* mir_in_b = (const float*)d_in[mix0 + 3];
  const float* mir_out_w= (const float*)d_in[mix0 + 4];
  const float* mir_out_b= (const float*)d_in[mix0 + 5];
  const float* mir_f1_w = (const float*)d_in[mix0 + 6];
  const float* mir_f1_b = (const float*)d_in[mix0 + 7];
  const float* mir_f2_w = (const float*)d_in[mix0 + 8];
  const float* mir_f2_b = (const float*)d_in[mix0 + 9];
  const float* mvis_ln_g = (const float*)d_in[mix0 + 10];
  const float* mvis_ln_b = (const float*)d_in[mix0 + 11];
  const float* mvis_in_w = (const float*)d_in[mix0 + 12];
  const float* mvis_in_b = (const float*)d_in[mix0 + 13];
  const float* mvis_out_w= (const float*)d_in[mix0 + 14];
  const float* mvis_out_b= (const float*)d_in[mix0 + 15];
  const float* mvis_f1_w = (const float*)d_in[mix0 + 16];
  const float* mvis_f1_b = (const float*)d_in[mix0 + 17];
  const float* mvis_f2_w = (const float*)d_in[mix0 + 18];
  const float* mvis_f2_b = (const float*)d_in[mix0 + 19];

  auto padded = [](size_t bytes) { return (bytes + 255) & ~(size_t)255; };
  size_t need2 = padded(2 * BNTC * 4)
               + padded(2 * BNTC * 2)
               + 3 * padded(2 * KVSTR * 2)
               + padded(2 * BNTC * 2)
               + padded(2 * BNTC * 4)
               + padded((size_t)2 * 786432 * 2)
               + padded((size_t)512 * 1024 * 2)
               + padded((size_t)BNT * 16 * 4)
               + padded((size_t)BNT * 8)
               + padded(64) + padded(64)
               + 3 * padded((size_t)BNT * 4)
               + padded((size_t)RCAP * 4)
               + 2 * padded((size_t)BNT * 4)
               + 2 * padded(64);
  int zc = (ws_size >= need2 + (1 << 20)) ? 2 : 1;

  char* ws = (char*)d_ws;
  size_t off = 0;
  auto alloc = [&](size_t bytes) {
    size_t o = off;
    off = (off + bytes + 255) & ~(size_t)255;
    return o;
  };
  size_t o_xc    = alloc(2 * BNTC * 4);
  size_t o_xn    = alloc((size_t)zc * BNTC * 2);
  size_t o_q     = alloc((size_t)zc * KVSTR * 2);
  size_t o_k     = alloc((size_t)zc * KVSTR * 2);
  size_t o_vt    = alloc((size_t)zc * KVSTR * 2);
  size_t o_attn  = alloc((size_t)zc * BNTC * 2);
  size_t o_rr    = alloc(2 * BNTC * 4);
  size_t o_wbf   = alloc((size_t)2 * 786432 * 2);
  size_t o_w2s   = alloc((size_t)512 * 1024 * 2);
  size_t o_hp    = alloc((size_t)BNT * 16 * 4);
  size_t o_w64   = alloc((size_t)BNT * 8);
  size_t o_t64   = alloc(64);
  size_t o_count = alloc(64);
  size_t o_w32   = alloc((size_t)BNT * 4);
  size_t o_soft  = alloc((size_t)BNT * 4);
  size_t o_act   = alloc((size_t)BNT * 4);
  size_t o_rlist = alloc((size_t)RCAP * 4);
  size_t o_aidx  = alloc((size_t)BNT * 4);
  size_t o_inv   = alloc((size_t)BNT * 4);
  size_t o_nact  = alloc(64);
  size_t o_npad  = alloc(64);
  (void)n_in; (void)out_size;

  float*  xc   = (float*)(ws + o_xc);
  unsigned short* xn   = (unsigned short*)(ws + o_xn);
  unsigned short* q    = (unsigned short*)(ws + o_q);
  unsigned short* k    = (unsigned short*)(ws + o_k);
  unsigned short* vt   = (unsigned short*)(ws + o_vt);
  unsigned short* attn = (unsigned short*)(ws + o_attn);
  unsigned short* hffn = (unsigned short*)(ws + o_q);
  float*  rr   = (float*)(ws + o_rr);
  unsigned short* A2 = (unsigned short*)(ws + o_rr);   // x_hi [BNT][512]; dead before EPI3 writes
  unsigned short* wbf  = (unsigned short*)(ws + o_wbf);
  unsigned short* W2   = (unsigned short*)(ws + o_w2s);
  float*  hpart = (float*)(ws + o_hp);
  double* w64  = (double*)(ws + o_w64);
  double* t64  = (double*)(ws + o_t64);
  int*    cnt  = (int*)(ws + o_count);
  int*    rcount = cnt + 8;
  float*  w32  = (float*)(ws + o_w32);
  float*  soft = (float*)(ws + o_soft);
  int*    act  = (int*)(ws + o_act);
  int*    rlist = (int*)(ws + o_rlist);
  int*    aidx = (int*)(ws + o_aidx);
  int*    invm = (int*)(ws + o_inv);
  int*    nact = (int*)(ws + o_nact);
  int*    npad = (int*)(ws + o_npad);

  const unsigned short* mir_in  = wbf;
  const unsigned short* mir_out = wbf + 196608;
  const unsigned short* mir_f1  = wbf + 262144;
  const unsigned short* mir_f2  = wbf + 524288;
  const unsigned short* vis_in  = wbf + 786432;
  const unsigned short* vis_out = wbf + 786432 + 196608;
  const unsigned short* vis_f1  = wbf + 786432 + 262144;
  const unsigned short* vis_f2  = wbf + 786432 + 524288;

  // --- independent setup (off the decision chain)
  hipMemsetAsync(cnt, 0, 16 * sizeof(int), stream);
  convert_weights<<<6144, 256, 0, stream>>>(mir_in_w, mir_out_w, mir_f1_w, mir_f2_w,
                                            mvis_in_w, mvis_out_w, mvis_f1_w, mvis_f2_w,
                                            wbf);
  split_w_kernel<<<1024, 256, 0, stream>>>(agent_w1, W2);
  split_x_kernel<<<dim3(36, 8, 8), 256, 0, stream>>>(f_ir, f_vis, A2);

  // --- agent decision chain
  agent_gemm<<<dim3(BNT / 128, 8), 256, 0, stream>>>(
      A2, W2, agent_b1, bn_gamma, bn_beta, bn_mean, bn_var, agent_w2, hpart);
  decide_kernel<<<8, 256, 0, stream>>>(
      hpart, agent_b2, hyp_w1, hyp_b1, hyp_w2, hyp_b2, w64, w32, t64, rcount, rlist);
  refine_kernel<<<RCAP, 1024, 0, stream>>>(
      f_ir, f_vis, agent_w1, agent_b1, bn_gamma, bn_beta, bn_mean, bn_var,
      agent_w2, agent_b2, rlist, rcount, w64, w32);
  compact_kernel<<<8, 256, 0, stream>>>(w64, t64, soft, act, aidx, invm, nact, npad);

  // --- gather both compact residual streams (z: 0=ir, 1=vis)
  gather_kernel<<<dim3(36, 8, 2), 256, 0, stream>>>(A2, aidx, npad, xc);

  if (zc == 2) {
    size_t WSTR = 786432;
    ln_kernel<<<dim3(BNT / 4, 2), 256, 0, stream>>>(
        xc, BNTC, mir_ln_g, mir_ln_b, mvis_ln_g, mvis_ln_b, 0, xn, BNTC, npad);
    gemm_bt<0><<<dim3(BNT / 128, 6, 2), 256, 0, stream>>>(
        xn, BNTC, mir_in, WSTR, mir_in_b, mvis_in_b, 0,
        nullptr, 0, nullptr, 0, nullptr, 0, q, k, vt, KVSTR, npad, 768, 256);
    flash_kernel<<<dim3(32, 36, 2), 256, 0, stream>>>(q, k, vt, nact, npad, attn);
    gemm_bt<1><<<dim3(BNT / 128, 2, 2), 256, 0, stream>>>(
        attn, BNTC, mir_out, WSTR, mir_out_b, mvis_out_b, 0,
        xc, BNTC, nullptr, 0, nullptr, 0, nullptr, nullptr, nullptr, 0, npad, 256, 256);
    ln_kernel<<<dim3(BNT / 4, 2), 256, 0, stream>>>(
        xc, BNTC, mir_ln_g, mir_ln_b, mvis_ln_g, mvis_ln_b, 0, xn, BNTC, npad);
    gemm_bt<2><<<dim3(BNT / 128, 8, 2), 256, 0, stream>>>(
        xn, BNTC, mir_f1, WSTR, mir_f1_b, mvis_f1_b, 0,
        nullptr, 0, nullptr, 0, hffn, HSTR, nullptr, nullptr, nullptr, 0, npad, 1024, 256);
    gemm_bt<3><<<dim3(BNT / 128, 2, 2), 256, 0, stream>>>(
        hffn, HSTR, mir_f2, WSTR, mir_f2_b, mvis_f2_b, 0,
        xc, BNTC, rr, BNTC, nullptr, 0, nullptr, nullptr, nullptr, 0, npad, 256, 1024);
  } else {
    for (int s = 0; s < 2; ++s) {
      const float* g   = s ? mvis_ln_g : mir_ln_g;
      const float* be  = s ? mvis_ln_b : mir_ln_b;
      const unsigned short* w_in  = s ? vis_in  : mir_in;
      const unsigned short* w_out = s ? vis_out : mir_out;
      const unsigned short* w_f1  = s ? vis_f1  : mir_f1;
      const unsigned short* w_f2  = s ? vis_f2  : mir_f2;
      const float* b_in  = s ? mvis_in_b  : mir_in_b;
      const float* b_out = s ? mvis_out_b : mir_out_b;
      const float* b_f1  = s ? mvis_f1_b  : mir_f1_b;
      const float* b_f2  = s ? mvis_f2_b  : mir_f2_b;
      float* xcs = xc + (size_t)s * BNTC;
      float* rrs = rr + (size_t)s * BNTC;
      ln_kernel<<<dim3(BNT / 4, 1), 256, 0, stream>>>(
          xcs, 0, g, be, g, be, 0, xn, 0, npad);
      gemm_bt<0><<<dim3(BNT / 128, 6, 1), 256, 0, stream>>>(
          xn, 0, w_in, 0, b_in, b_in, 0,
          nullptr, 0, nullptr, 0, nullptr, 0, q, k, vt, 0, npad, 768, 256);
      flash_kernel<<<dim3(32, 36, 1), 256, 0, stream>>>(q, k, vt, nact, npad, attn);
      gemm_bt<1><<<dim3(BNT / 128, 2, 1), 256, 0, stream>>>(
          attn, 0, w_out, 0, b_out, b_out, 0,
          xcs, 0, nullptr, 0, nullptr, 0, nullptr, nullptr, nullptr, 0, npad, 256, 256);
      ln_kernel<<<dim3(BNT / 4, 1), 256, 0, stream>>>(
          xcs, 0, g, be, g, be, 0, xn, 0, npad);
      gemm_bt<2><<<dim3(BNT / 128, 8, 1), 256, 0, stream>>>(
          xn, 0, w_f1, 0, b_f1, b_f1, 0,
          nullptr, 0, nullptr, 0, hffn, 0, nullptr, nullptr, nullptr, 0, npad, 1024, 256);
      gemm_bt<3><<<dim3(BNT / 128, 2, 1), 256, 0, stream>>>(
          hffn, 0, w_f2, 0, b_f2, b_f2, 0,
          xcs, 0, rrs, 0, nullptr, 0, nullptr, nullptr, nullptr, 0, npad, 256, 1024);
    }
  }

  // --- final fusion + aux loss
  final_kernel<<<dim3(36, 4, 8), 256, 0, stream>>>(
      f_ir, f_vis, rr, rr + BNTC, w32, soft, invm, hs_ptr, (float*)d_out);
}

// Round 13
// 232.225 us; speedup vs baseline: 1.5982x; 1.0347x over previous
//
#include <hip/hip_runtime.h>
#include <hip/hip_bf16.h>
#include <cstdint>
#include <cstddef>

typedef __attribute__((ext_vector_type(8))) short short8;
typedef __attribute__((ext_vector_type(4))) short s16x4;
typedef __attribute__((ext_vector_type(4))) float f32x4;

#define DEVI static __device__ __forceinline__

constexpr int NB   = 8;
constexpr int CDIM = 256;
constexpr int NTOK = 2304;          // 48*48
constexpr int BNT  = NB * NTOK;     // 18432
constexpr int HIDN = 512;
constexpr int RCAP = 4096;          // refine-list capacity
constexpr size_t BNTC = (size_t)BNT * CDIM;          // 4,718,592 elements
constexpr size_t KVSTR = (size_t)32 * NTOK * 64;     // q/k/vt per-z stride (elements)
constexpr size_t HSTR  = (size_t)BNT * 1024;         // hffn per-z stride (elements)

DEVI unsigned short f2bf(float f) {
  unsigned u = __builtin_bit_cast(unsigned, f);
  unsigned r = 0x7FFFu + ((u >> 16) & 1u);
  return (unsigned short)((u + r) >> 16);
}
DEVI float bf2f(unsigned short h) {
  unsigned u = ((unsigned)h) << 16;
  return __builtin_bit_cast(float, u);
}

// ---------------------------------------------------------------- weights->bf16
__global__ __launch_bounds__(256) void convert_weights(
    const float* __restrict__ miw, const float* __restrict__ mow,
    const float* __restrict__ mf1, const float* __restrict__ mf2,
    const float* __restrict__ viw, const float* __restrict__ vow,
    const float* __restrict__ vf1, const float* __restrict__ vf2,
    unsigned short* __restrict__ dst)
{
  int i = blockIdx.x * 256 + threadIdx.x;
  int m = i / 786432;
  int r = i % 786432;
  const float* src; int off;
  if      (r < 196608) { src = m ? viw : miw; off = r; }
  else if (r < 262144) { src = m ? vow : mow; off = r - 196608; }
  else if (r < 524288) { src = m ? vf1 : mf1; off = r - 262144; }
  else                 { src = m ? vf2 : mf2; off = r - 524288; }
  dst[i] = f2bf(src[off]);
}

// ---------------------------------------------------------------- agent W1 -> bf16x2 split [512][1024]
__global__ __launch_bounds__(256) void split_w_kernel(
    const float* __restrict__ w1, unsigned short* __restrict__ W2)
{
  int i = blockIdx.x * 256 + threadIdx.x;
  int n = i >> 9, k = i & 511;
  float v = w1[i];
  unsigned short hi = f2bf(v);
  float r1 = v - bf2f(hi);
  unsigned short mid = f2bf(r1);
  size_t base = (size_t)n * 1024 + k;
  W2[base] = hi; W2[base + 512] = mid;
}

// ---------------------------------------------------------------- x -> bf16 hi plane, pixel-major [BNT][512]
__global__ __launch_bounds__(256) void split_x_kernel(
    const float* __restrict__ f_ir, const float* __restrict__ f_vis,
    unsigned short* __restrict__ A2)
{
  __shared__ float tile[64][65];
  int n0 = blockIdx.x * 64, c0 = blockIdx.y * 64, b = blockIdx.z;
  int tid = threadIdx.x;
  const float* src = (c0 < 256) ? f_ir : f_vis;
  int cc0 = c0 & 255;
#pragma unroll
  for (int i = 0; i < 16; ++i) {
    int l = tid + i * 256;
    int r = l >> 6, col = l & 63;
    tile[r][col] = src[((size_t)b * 256 + cc0 + r) * NTOK + n0 + col];
  }
  __syncthreads();
#pragma unroll
  for (int i = 0; i < 16; ++i) {
    int l = tid + i * 256;
    int r = l >> 6, col = l & 63;
    A2[((size_t)b * NTOK + n0 + r) * 512 + c0 + col] = f2bf(tile[col][r]);
  }
}

// ---------------------------------------------------------------- agent GEMM (128x64) single-pass x_hi x (W_hi|W_mid) + fused epilogue
__global__ __launch_bounds__(256) void agent_gemm(
    const unsigned short* __restrict__ A2, const unsigned short* __restrict__ W2,
    const float* __restrict__ b1,
    const float* __restrict__ bng, const float* __restrict__ bnb,
    const float* __restrict__ bnm, const float* __restrict__ bnv,
    const float* __restrict__ w2, float* __restrict__ hpart)
{
  __shared__ unsigned short As[128][72];
  __shared__ unsigned short Ws[128][72];   // rows 0-63: W-hi, rows 64-127: W-mid
  __shared__ float scl[64], shl[64], w2l[64];
  int tid = threadIdx.x;
  int lane = tid & 63, wid = tid >> 6;
  int wm = (wid >> 1) * 64, wn = (wid & 1) * 32;
  int m0 = blockIdx.x * 128, n0 = blockIdx.y * 64;
  if (tid < 64) {
    int n = n0 + tid;
    double inv = 1.0 / sqrt((double)bnv[n] + 1e-5);
    double sc = (double)bng[n] * inv;
    scl[tid] = (float)sc;
    shl[tid] = (float)(((double)b1[n] - (double)bnm[n]) * sc + (double)bnb[n]);
    w2l[tid] = w2[n];
  }
  f32x4 zero = {0.f, 0.f, 0.f, 0.f};
  f32x4 acc[4][2];
#pragma unroll
  for (int i = 0; i < 4; ++i)
#pragma unroll
    for (int j = 0; j < 2; ++j) acc[i][j] = zero;

  for (int kin = 0; kin < 512; kin += 64) {
    __syncthreads();
#pragma unroll
    for (int i = 0; i < 4; ++i) {
      int l = tid + i * 256;
      int r = l >> 3, ch = (l & 7) * 8;
      *(short8*)&As[r][ch] = *(const short8*)&A2[(size_t)(m0 + r) * 512 + kin + ch];
    }
#pragma unroll
    for (int i = 0; i < 4; ++i) {
      int l = tid + i * 256;
      int r = l >> 3, ch = (l & 7) * 8;
      int wr = (r < 64) ? r : (r - 64);
      int wo = (r < 64) ? 0 : 512;
      *(short8*)&Ws[r][ch] = *(const short8*)&W2[(size_t)(n0 + wr) * 1024 + wo + kin + ch];
    }
    __syncthreads();
#pragma unroll
    for (int ks = 0; ks < 2; ++ks) {
      short8 a[4], bh[2], bm[2];
#pragma unroll
      for (int i = 0; i < 4; ++i)
        a[i] = *(const short8*)&As[wm + i * 16 + (lane & 15)][ks * 32 + (lane >> 4) * 8];
#pragma unroll
      for (int j = 0; j < 2; ++j) {
        bh[j] = *(const short8*)&Ws[wn + j * 16 + (lane & 15)][ks * 32 + (lane >> 4) * 8];
        bm[j] = *(const short8*)&Ws[64 + wn + j * 16 + (lane & 15)][ks * 32 + (lane >> 4) * 8];
      }
#pragma unroll
      for (int i = 0; i < 4; ++i)
#pragma unroll
        for (int j = 0; j < 2; ++j) {
          acc[i][j] = __builtin_amdgcn_mfma_f32_16x16x32_bf16(a[i], bh[j], acc[i][j], 0, 0, 0);
          acc[i][j] = __builtin_amdgcn_mfma_f32_16x16x32_bf16(a[i], bm[j], acc[i][j], 0, 0, 0);
        }
    }
  }

  int rbase = (lane >> 4) * 4;
  int cbase = lane & 15;
  float part[4][4];
#pragma unroll
  for (int i = 0; i < 4; ++i) {
#pragma unroll
    for (int r = 0; r < 4; ++r) {
      float p = 0.f;
#pragma unroll
      for (int j = 0; j < 2; ++j) {
        int nl = wn + j * 16 + cbase;
        float val = acc[i][j][r] * scl[nl] + shl[nl];
        if (val > 0.f) p += val * w2l[nl];
      }
      part[i][r] = p;
    }
  }
#pragma unroll
  for (int msk = 1; msk < 16; msk <<= 1) {
#pragma unroll
    for (int i = 0; i < 4; ++i)
#pragma unroll
      for (int r = 0; r < 4; ++r)
        part[i][r] += __shfl_xor(part[i][r], msk);
  }
  if (cbase == 0) {
    int slot = blockIdx.y * 2 + (wid & 1);
#pragma unroll
    for (int i = 0; i < 4; ++i)
#pragma unroll
      for (int r = 0; r < 4; ++r) {
        int mm = m0 + wm + i * 16 + rbase + r;
        hpart[(size_t)mm * 16 + slot] = part[i][r];
      }
  }
}

// ---------------------------------------------------------------- decide: partials -> w (sigmoid), mean -> t, flag window (wave-agg)
__global__ __launch_bounds__(256) void decide_kernel(
    const float* __restrict__ hpart, const float* __restrict__ b2,
    const float* __restrict__ hw1, const float* __restrict__ hb1,
    const float* __restrict__ hw2, const float* __restrict__ hb2,
    double* __restrict__ w64, float* __restrict__ w32, double* __restrict__ t64,
    int* __restrict__ rcount, int* __restrict__ rlist)
{
  __shared__ double red[256];
  __shared__ double tsh;
  int b = blockIdx.x, tid = threadIdx.x, lane = tid & 63;
  unsigned long long ltmask = (1ull << lane) - 1ull;
  double wloc[9];
  double s = 0.0;
#pragma unroll
  for (int c = 0; c < 9; ++c) {
    int pix = b * NTOK + c * 256 + tid;
    const float* hp = hpart + (size_t)pix * 16;
    double lg = (double)b2[0];
#pragma unroll
    for (int j = 0; j < 16; ++j) lg += (double)hp[j];
    double wd = 1.0 / (1.0 + exp(-lg));
    w64[pix] = wd; w32[pix] = (float)wd;
    wloc[c] = wd;
    s += wd;
  }
  red[tid] = s;
  __syncthreads();
  for (int st = 128; st; st >>= 1) {
    if (tid < st) red[tid] += red[tid + st];
    __syncthreads();
  }
  if (tid == 0) {
    double g = red[0] / 2304.0;
    double acc = (double)hb2[0];
    for (int j = 0; j < 16; ++j) {
      double hh = g * (double)hw1[j] + (double)hb1[j];
      hh = hh > 0.0 ? hh : 0.0;
      acc += hh * (double)hw2[j];
    }
    tsh = 1.0 / (1.0 + exp(-acc));
    t64[b] = tsh;
  }
  __syncthreads();
  double t = tsh;
#pragma unroll
  for (int c = 0; c < 9; ++c) {
    int flag = fabs(wloc[c] - t) < 4e-4 ? 1 : 0;
    unsigned long long ball = __ballot(flag);
    if (ball) {
      int leader = __ffsll((long long)ball) - 1;
      int base = 0;
      if (lane == leader) base = atomicAdd(rcount, __popcll(ball));
      base = __shfl(base, leader);
      if (flag) {
        int idx = base + __popcll(ball & ltmask);
        if (idx < RCAP) rlist[idx] = b * NTOK + c * 256 + tid;
      }
    }
  }
}

// ---------------------------------------------------------------- fp64 recompute of flagged pixels (1 pixel/block, 16 waves, 8-way ILP)
__global__ __launch_bounds__(1024) void refine_kernel(
    const float* __restrict__ f_ir, const float* __restrict__ f_vis,
    const float* __restrict__ w1, const float* __restrict__ b1,
    const float* __restrict__ bng, const float* __restrict__ bnb,
    const float* __restrict__ bnm, const float* __restrict__ bnv,
    const float* __restrict__ w2, const float* __restrict__ b2,
    const int* __restrict__ rlist, const int* __restrict__ rcount,
    double* __restrict__ w64, float* __restrict__ w32)
{
  int nr = rcount[0]; if (nr > RCAP) nr = RCAP;
  if ((int)blockIdx.x >= nr) return;
  int pix = rlist[blockIdx.x];
  int b = pix / NTOK, n = pix % NTOK;
  __shared__ double xs[512];
  __shared__ double scs[512], shs[512];
  __shared__ double lred[16];
  int tid = threadIdx.x, lane = tid & 63, wid = tid >> 6;   // 16 waves
  if (tid < 512) {
    const float* fsrc = (tid < 256) ? f_ir : f_vis;
    xs[tid] = (double)fsrc[((size_t)b * 256 + (tid & 255)) * NTOK + n];
    double inv = 1.0 / sqrt((double)bnv[tid] + 1e-5);
    double sc = (double)bng[tid] * inv;
    scs[tid] = sc;
    shs[tid] = ((double)b1[tid] - (double)bnm[tid]) * sc + (double)bnb[tid];
  }
  __syncthreads();
  double xp[8];
#pragma unroll
  for (int j = 0; j < 8; ++j) xp[j] = xs[lane * 8 + j];
  double lg = 0.0;
  for (int oo = 0; oo < 32; oo += 8) {            // each wave owns 32 outputs
    int o = wid * 32 + oo;
    double s[8] = {0, 0, 0, 0, 0, 0, 0, 0};
    const float* wr = w1 + (size_t)o * 512 + lane * 8;
#pragma unroll
    for (int t = 0; t < 8; ++t) {
#pragma unroll
      for (int j = 0; j < 8; ++j)
        s[t] += (double)wr[t * 512 + j] * xp[j];
    }
#pragma unroll
    for (int m = 1; m < 64; m <<= 1) {
#pragma unroll
      for (int t = 0; t < 8; ++t) s[t] += __shfl_xor(s[t], m);
    }
#pragma unroll
    for (int t = 0; t < 8; ++t) {
      int ot = o + t;
      double hv = s[t] * scs[ot] + shs[ot];
      if (hv > 0.0) lg += hv * (double)w2[ot];
    }
  }
  if (lane == 0) lred[wid] = lg;
  __syncthreads();
  if (tid == 0) {
    double L = (double)b2[0];
#pragma unroll
    for (int w = 0; w < 16; ++w) L += lred[w];
    double wd = 1.0 / (1.0 + exp(-L));
    w64[pix] = wd;
    w32[pix] = (float)wd;
  }
}

// ---------------------------------------------------------------- compaction (mask+soft fused, top-64 fallback) + inverse map
__global__ __launch_bounds__(256) void compact_kernel(
    const double* __restrict__ w64, const double* __restrict__ t64,
    float* __restrict__ soft, int* __restrict__ active, int* __restrict__ actidx,
    int* __restrict__ invmap, int* __restrict__ nact, int* __restrict__ npad)
{
  __shared__ double wv[NTOK];
  __shared__ double rv[256];
  __shared__ int   ri[256];
  __shared__ int wtot[9][4];
  int b = blockIdx.x, tid = threadIdx.x, lane = tid & 63, wid = tid >> 6;
  double t = t64[b];
  unsigned long long ltmask = (1ull << lane) - 1ull;

  int sbase = 0;
  for (int c = 0; c < 9; ++c) {
    int i = c * 256 + tid;
    double wd = w64[(size_t)b * NTOK + i];
    double sd = 1.0 / (1.0 + exp(-(wd - t) * 50.0));
    soft[(size_t)b * NTOK + i] = (float)sd;
    int a = sd > 0.5 ? 1 : 0;
    active[(size_t)b * NTOK + i] = a;
    unsigned long long ball = __ballot(a);
    int wpre = __popcll(ball & ltmask);
    if (lane == 0) wtot[c][wid] = __popcll(ball);
    __syncthreads();
    int cross = 0;
    for (int w = 0; w < wid; ++w) cross += wtot[c][w];
    int slot = sbase + cross + wpre;
    if (a) actidx[(size_t)b * NTOK + slot] = i;
    invmap[(size_t)b * NTOK + i] = a ? slot : -1;
    sbase += wtot[c][0] + wtot[c][1] + wtot[c][2] + wtot[c][3];
  }

  if (sbase < 64) {
    for (int i = tid; i < NTOK; i += 256) {
      wv[i] = w64[(size_t)b * NTOK + i];
      active[(size_t)b * NTOK + i] = 0;
    }
    __syncthreads();
    for (int it = 0; it < 64; ++it) {
      double best = -1e300; int bi = 1 << 30;
      for (int i = tid; i < NTOK; i += 256) {
        double vvv = wv[i];
        if (vvv > best || (vvv == best && i < bi)) { best = vvv; bi = i; }
      }
      rv[tid] = best; ri[tid] = bi;
      __syncthreads();
      for (int st = 128; st; st >>= 1) {
        if (tid < st) {
          if (rv[tid + st] > rv[tid] ||
              (rv[tid + st] == rv[tid] && ri[tid + st] < ri[tid])) {
            rv[tid] = rv[tid + st]; ri[tid] = ri[tid + st];
          }
        }
        __syncthreads();
      }
      if (tid == 0) { active[(size_t)b * NTOK + ri[0]] = 1; wv[ri[0]] = -1e300; }
      __syncthreads();
    }
    sbase = 0;
    for (int c = 0; c < 9; ++c) {
      int i = c * 256 + tid;
      int a = active[(size_t)b * NTOK + i];
      unsigned long long ball = __ballot(a);
      int wpre = __popcll(ball & ltmask);
      if (lane == 0) wtot[c][wid] = __popcll(ball);
      __syncthreads();
      int cross = 0;
      for (int w = 0; w < wid; ++w) cross += wtot[c][w];
      int slot = sbase + cross + wpre;
      if (a) actidx[(size_t)b * NTOK + slot] = i;
      invmap[(size_t)b * NTOK + i] = a ? slot : -1;
      sbase += wtot[c][0] + wtot[c][1] + wtot[c][2] + wtot[c][3];
    }
  }
  int n = sbase;
  int np = (n + 127) & ~127;
  if (np > NTOK) np = NTOK;
  for (int i = n + tid; i < np; i += 256) actidx[(size_t)b * NTOK + i] = -1;
  if (tid == 0) { nact[b] = n; npad[b] = np; }
}

// ---------------------------------------------------------------- fused gather + first LayerNorm (1 wave/token, z via blockIdx.y)
__global__ __launch_bounds__(256) void gatherln_kernel(
    const unsigned short* __restrict__ A2, const int* __restrict__ actidx,
    const int* __restrict__ npad,
    const float* __restrict__ g0, const float* __restrict__ be0,
    const float* __restrict__ g1, const float* __restrict__ be1,
    float* __restrict__ xc, unsigned short* __restrict__ xn)
{
  int z = blockIdx.y;
  xc += (size_t)z * BNTC; xn += (size_t)z * BNTC;
  const float* gamma = z ? g1 : g0;
  const float* beta  = z ? be1 : be0;
  int lane = threadIdx.x & 63, wid = threadIdx.x >> 6;
  int tok = blockIdx.x * 4 + wid;
  int b = tok / NTOK;
  int i = tok - b * NTOK;
  if (i >= npad[b]) return;
  int src = actidx[(size_t)b * NTOK + i];
  f32x4 v = {0.f, 0.f, 0.f, 0.f};
  if (src >= 0) {
    const unsigned short* p = A2 + ((size_t)b * NTOK + src) * 512 + z * 256 + lane * 4;
    s16x4 hi = *(const s16x4*)p;
#pragma unroll
    for (int j = 0; j < 4; ++j) v[j] = bf2f((unsigned short)hi[j]);
  }
  *(f32x4*)&xc[(size_t)tok * 256 + lane * 4] = v;
  float s = v[0] + v[1] + v[2] + v[3];
#pragma unroll
  for (int m = 1; m < 64; m <<= 1) s += __shfl_xor(s, m);
  float mu = s * (1.f / 256.f);
  float vs = 0.f;
#pragma unroll
  for (int j = 0; j < 4; ++j) { float d = v[j] - mu; vs += d * d; }
#pragma unroll
  for (int m = 1; m < 64; m <<= 1) vs += __shfl_xor(vs, m);
  float rs = rsqrtf(vs * (1.f / 256.f) + 1e-5f);
  f32x4 gg = *(const f32x4*)&gamma[lane * 4];
  f32x4 bb = *(const f32x4*)&beta[lane * 4];
  unsigned short r0 = f2bf((v[0] - mu) * rs * gg[0] + bb[0]);
  unsigned short r1 = f2bf((v[1] - mu) * rs * gg[1] + bb[1]);
  unsigned short r2 = f2bf((v[2] - mu) * rs * gg[2] + bb[2]);
  unsigned short r3 = f2bf((v[3] - mu) * rs * gg[3] + bb[3]);
  uint2 pk;
  pk.x = (unsigned)r0 | ((unsigned)r1 << 16);
  pk.y = (unsigned)r2 | ((unsigned)r3 << 16);
  *(uint2*)&xn[(size_t)tok * 256 + lane * 4] = pk;
}

// ---------------------------------------------------------------- gather compact rows from x_hi (bf16 -> f32); z = ir/vis (zc==1 path)
__global__ __launch_bounds__(256) void gather_kernel(
    const unsigned short* __restrict__ A2, const int* __restrict__ actidx,
    const int* __restrict__ npad, float* __restrict__ xc)
{
  int b = blockIdx.y, i0 = blockIdx.x * 64, z = blockIdx.z;
  int cofs = z * 256;
  xc += (size_t)z * BNTC;
  if (i0 >= npad[b]) return;
  __shared__ int idx[64];
  int tid = threadIdx.x;
  if (tid < 64) idx[tid] = actidx[(size_t)b * NTOK + i0 + tid];
  __syncthreads();
#pragma unroll
  for (int it = 0; it < 16; ++it) {
    int s = tid + it * 256;
    int r = s >> 6, q4 = (s & 63) * 4;
    int src = idx[r];
    f32x4 v = {0.f, 0.f, 0.f, 0.f};
    if (src >= 0) {
      const unsigned short* p = A2 + ((size_t)b * NTOK + src) * 512 + cofs + q4;
      s16x4 hi = *(const s16x4*)&p[0];
#pragma unroll
      for (int j = 0; j < 4; ++j)
        v[j] = bf2f((unsigned short)hi[j]);
    }
    *(f32x4*)&xc[((size_t)b * NTOK + i0 + r) * 256 + q4] = v;
  }
}

// ---------------------------------------------------------------- LayerNorm, z via blockIdx.y
__global__ __launch_bounds__(256) void ln_kernel(
    const float* __restrict__ x, size_t xstr,
    const float* __restrict__ g0, const float* __restrict__ be0,
    const float* __restrict__ g1, const float* __restrict__ be1, int zbase,
    unsigned short* __restrict__ out, size_t ostr, const int* __restrict__ npad)
{
  int z = blockIdx.y;
  x += (size_t)z * xstr; out += (size_t)z * ostr;
  const float* gamma = ((zbase + z) & 1) ? g1 : g0;
  const float* beta  = ((zbase + z) & 1) ? be1 : be0;
  int lane = threadIdx.x & 63, wid = threadIdx.x >> 6;
  int tok = blockIdx.x * 4 + wid;
  int b = tok / NTOK;
  if ((tok - b * NTOK) >= npad[b]) return;
  const float* xp = x + (size_t)tok * 256;
  f32x4 v = *(const f32x4*)&xp[lane * 4];
  float s = v[0] + v[1] + v[2] + v[3];
#pragma unroll
  for (int m = 1; m < 64; m <<= 1) s += __shfl_xor(s, m);
  float mu = s * (1.f / 256.f);
  float vs = 0.f;
#pragma unroll
  for (int j = 0; j < 4; ++j) { float d = v[j] - mu; vs += d * d; }
#pragma unroll
  for (int m = 1; m < 64; m <<= 1) vs += __shfl_xor(vs, m);
  float rs = rsqrtf(vs * (1.f / 256.f) + 1e-5f);
  f32x4 gg = *(const f32x4*)&gamma[lane * 4];
  f32x4 bb = *(const f32x4*)&beta[lane * 4];
  unsigned short r0 = f2bf((v[0] - mu) * rs * gg[0] + bb[0]);
  unsigned short r1 = f2bf((v[1] - mu) * rs * gg[1] + bb[1]);
  unsigned short r2 = f2bf((v[2] - mu) * rs * gg[2] + bb[2]);
  unsigned short r3 = f2bf((v[3] - mu) * rs * gg[3] + bb[3]);
  uint2 pk;
  pk.x = (unsigned)r0 | ((unsigned)r1 << 16);
  pk.y = (unsigned)r2 | ((unsigned)r3 << 16);
  *(uint2*)&out[(size_t)tok * 256 + lane * 4] = pk;
}

// ---------------------------------------------------------------- bf16 GEMM on compact rows, z via blockIdx.z
// EPI: 0=qkv scatter, 1=proj+residual, 2=gelu->bf16, 3=ffn2+residual -> compact refined
template <int EPI>
__global__ __launch_bounds__(256) void gemm_bt(
    const unsigned short* __restrict__ A, size_t astr,
    const unsigned short* __restrict__ Wt, size_t wstr,
    const float* __restrict__ biasA, const float* __restrict__ biasB, int zbase,
    float* __restrict__ xres, size_t xstr,
    float* __restrict__ fout, size_t fstr,
    unsigned short* __restrict__ bout, size_t bstr,
    unsigned short* __restrict__ qb, unsigned short* __restrict__ kb,
    unsigned short* __restrict__ vtb, size_t qstr,
    const int* __restrict__ npad, int N, int K)
{
  int z = blockIdx.z;
  A += (size_t)z * astr;
  Wt += (size_t)z * wstr;
  const float* bias = ((zbase + z) & 1) ? biasB : biasA;
  if (EPI == 0) { qb += (size_t)z * qstr; kb += (size_t)z * qstr; vtb += (size_t)z * qstr; }
  if (EPI == 1 || EPI == 3) xres += (size_t)z * xstr;
  if (EPI == 3) fout += (size_t)z * fstr;
  if (EPI == 2) bout += (size_t)z * bstr;

  int m0 = blockIdx.x * 128, n0 = blockIdx.y * 128;
  int bb = m0 / NTOK;
  if ((m0 - bb * NTOK) >= npad[bb]) return;
  __shared__ unsigned short As[128][72];
  __shared__ unsigned short Ws[128][72];
  int tid = threadIdx.x;
  int lane = tid & 63, wid = tid >> 6;
  int wm = (wid >> 1) * 64, wn = (wid & 1) * 64;
  f32x4 zero = {0.f, 0.f, 0.f, 0.f};
  f32x4 acc[4][4];
#pragma unroll
  for (int i = 0; i < 4; ++i)
#pragma unroll
    for (int j = 0; j < 4; ++j) acc[i][j] = zero;

  for (int kc = 0; kc < K; kc += 64) {
#pragma unroll
    for (int i = 0; i < 4; ++i) {
      int l = tid + i * 256;
      int r = l >> 3, ch = (l & 7) * 8;
      *(short8*)&As[r][ch] = *(const short8*)&A[(size_t)(m0 + r) * K + kc + ch];
      *(short8*)&Ws[r][ch] = *(const short8*)&Wt[(size_t)(n0 + r) * K + kc + ch];
    }
    __syncthreads();
#pragma unroll
    for (int ks = 0; ks < 2; ++ks) {
      short8 a[4], bf[4];
#pragma unroll
      for (int i = 0; i < 4; ++i)
        a[i] = *(const short8*)&As[wm + i * 16 + (lane & 15)][ks * 32 + (lane >> 4) * 8];
#pragma unroll
      for (int j = 0; j < 4; ++j)
        bf[j] = *(const short8*)&Ws[wn + j * 16 + (lane & 15)][ks * 32 + (lane >> 4) * 8];
#pragma unroll
      for (int i = 0; i < 4; ++i)
#pragma unroll
        for (int j = 0; j < 4; ++j)
          acc[i][j] = __builtin_amdgcn_mfma_f32_16x16x32_bf16(a[i], bf[j], acc[i][j], 0, 0, 0);
    }
    __syncthreads();
  }

  int rbase = (lane >> 4) * 4;
  int cbase = lane & 15;
  if (EPI == 0) {
#pragma unroll
    for (int i = 0; i < 4; ++i) {
#pragma unroll
      for (int j = 0; j < 4; ++j) {
        int n = n0 + wn + j * 16 + cbase;
        int sect = n >> 8, hh = (n & 255) >> 6, d = n & 63;
        int mA = m0 + wm + i * 16 + rbase;
        int b = mA / NTOK, tok0 = mA % NTOK;
        size_t bh = (size_t)(b * 4 + hh);
        float vals[4];
#pragma unroll
        for (int r = 0; r < 4; ++r) vals[r] = acc[i][j][r] + bias[n];
        if (sect == 0) {
#pragma unroll
          for (int r = 0; r < 4; ++r)
            qb[(bh * NTOK + tok0 + r) * 64 + d] = f2bf(vals[r] * 0.125f);
        } else if (sect == 1) {
#pragma unroll
          for (int r = 0; r < 4; ++r)
            kb[(bh * NTOK + tok0 + r) * 64 + d] = f2bf(vals[r]);
        } else {
          unsigned short p0 = f2bf(vals[0]), p1 = f2bf(vals[1]);
          unsigned short p2 = f2bf(vals[2]), p3 = f2bf(vals[3]);
          uint2 pk;
          pk.x = (unsigned)p0 | ((unsigned)p1 << 16);
          pk.y = (unsigned)p2 | ((unsigned)p3 << 16);
          *(uint2*)&vtb[(bh * 64 + d) * NTOK + tok0] = pk;
        }
      }
    }
  } else {
#pragma unroll
    for (int i = 0; i < 4; ++i) {
#pragma unroll
      for (int j = 0; j < 4; ++j) {
#pragma unroll
        for (int r = 0; r < 4; ++r) {
          int m = m0 + wm + i * 16 + rbase + r;
          int n = n0 + wn + j * 16 + cbase;
          float v = acc[i][j][r] + bias[n];
          size_t idx = (size_t)m * N + n;
          if (EPI == 1) {
            xres[idx] += v;
          } else if (EPI == 2) {
            float g = 0.5f * v * (1.f + erff(v * 0.70710678118654752f));
            bout[idx] = f2bf(g);
          } else {
            fout[idx] = xres[idx] + v;
          }
        }
      }
    }
  }
}

// ---------------------------------------------------------------- flash attention over compact active keys, z via blockIdx.z
__global__ __launch_bounds__(256) void flash_kernel(
    const unsigned short* __restrict__ Q, const unsigned short* __restrict__ Kt,
    const unsigned short* __restrict__ VT, const int* __restrict__ nact,
    const int* __restrict__ npad, unsigned short* __restrict__ attnout)
{
  int z = blockIdx.z;
  Q += (size_t)z * KVSTR; Kt += (size_t)z * KVSTR; VT += (size_t)z * KVSTR;
  attnout += (size_t)z * BNTC;
  int bh = blockIdx.x, qt = blockIdx.y;
  int b = bh >> 2, h = bh & 3;
  int np = npad[b], na = nact[b];
  if (qt * 64 >= np) return;
  __shared__ unsigned short Ks[64][72];
  __shared__ unsigned short Vs[64][72];
  __shared__ unsigned short Ps[4][16][72];
  __shared__ float madd[64];
  int tid = threadIdx.x, lane = tid & 63, wid = tid >> 6;
  int qrow = qt * 64 + wid * 16 + (lane & 15);
  const unsigned short* qptr = Q + ((size_t)bh * NTOK + qrow) * 64;
  short8 aq0 = *(const short8*)&qptr[(lane >> 4) * 8];
  short8 aq1 = *(const short8*)&qptr[32 + (lane >> 4) * 8];
  f32x4 zero = {0.f, 0.f, 0.f, 0.f};
  f32x4 o[4];
  float mrow[4], lrow[4];
#pragma unroll
  for (int n = 0; n < 4; ++n) o[n] = zero;
#pragma unroll
  for (int r = 0; r < 4; ++r) { mrow[r] = -INFINITY; lrow[r] = 0.f; }
  const unsigned short* kbase = Kt + (size_t)bh * NTOK * 64;
  const unsigned short* vbase = VT + (size_t)bh * 64 * NTOK;
  int nkt = (na + 63) >> 6;

  for (int kt = 0; kt < nkt; ++kt) {
    int k0 = kt * 64;
#pragma unroll
    for (int i = 0; i < 2; ++i) {
      int l = tid + i * 256;
      int r = l >> 3, ch = (l & 7) * 8;
      *(short8*)&Ks[r][ch] = *(const short8*)&kbase[(size_t)(k0 + r) * 64 + ch];
      *(short8*)&Vs[r][ch] = *(const short8*)&vbase[(size_t)r * NTOK + k0 + ch];
    }
    if (tid < 64) madd[tid] = (k0 + tid < na) ? 0.f : -1e9f;
    __syncthreads();

    f32x4 s[4];
#pragma unroll
    for (int n = 0; n < 4; ++n) s[n] = zero;
#pragma unroll
    for (int n = 0; n < 4; ++n) {
      short8 bk0 = *(const short8*)&Ks[n * 16 + (lane & 15)][(lane >> 4) * 8];
      short8 bk1 = *(const short8*)&Ks[n * 16 + (lane & 15)][32 + (lane >> 4) * 8];
      s[n] = __builtin_amdgcn_mfma_f32_16x16x32_bf16(aq0, bk0, s[n], 0, 0, 0);
      s[n] = __builtin_amdgcn_mfma_f32_16x16x32_bf16(aq1, bk1, s[n], 0, 0, 0);
    }
    float pm[4] = {-INFINITY, -INFINITY, -INFINITY, -INFINITY};
#pragma unroll
    for (int n = 0; n < 4; ++n) {
      float ca = madd[n * 16 + (lane & 15)];
#pragma unroll
      for (int r = 0; r < 4; ++r) {
        s[n][r] += ca;
        pm[r] = fmaxf(pm[r], s[n][r]);
      }
    }
#pragma unroll
    for (int r = 0; r < 4; ++r) {
#pragma unroll
      for (int msk = 1; msk < 16; msk <<= 1)
        pm[r] = fmaxf(pm[r], __shfl_xor(pm[r], msk));
    }
    float sf[4], psum[4];
#pragma unroll
    for (int r = 0; r < 4; ++r) {
      float mn = fmaxf(mrow[r], pm[r]);
      sf[r] = __expf(mrow[r] - mn);
      mrow[r] = mn;
      psum[r] = 0.f;
    }
#pragma unroll
    for (int n = 0; n < 4; ++n)
#pragma unroll
      for (int r = 0; r < 4; ++r) {
        float p = __expf(s[n][r] - mrow[r]);
        s[n][r] = p;
        psum[r] += p;
      }
#pragma unroll
    for (int r = 0; r < 4; ++r) {
#pragma unroll
      for (int msk = 1; msk < 16; msk <<= 1)
        psum[r] += __shfl_xor(psum[r], msk);
      lrow[r] = lrow[r] * sf[r] + psum[r];
    }
#pragma unroll
    for (int n = 0; n < 4; ++n)
#pragma unroll
      for (int r = 0; r < 4; ++r) o[n][r] *= sf[r];
#pragma unroll
    for (int n = 0; n < 4; ++n)
#pragma unroll
      for (int r = 0; r < 4; ++r)
        Ps[wid][(lane >> 4) * 4 + r][n * 16 + (lane & 15)] = f2bf(s[n][r]);
    asm volatile("s_waitcnt lgkmcnt(0)" ::: "memory");
    __builtin_amdgcn_sched_barrier(0);
    short8 ap0 = *(const short8*)&Ps[wid][lane & 15][(lane >> 4) * 8];
    short8 ap1 = *(const short8*)&Ps[wid][lane & 15][32 + (lane >> 4) * 8];
#pragma unroll
    for (int n = 0; n < 4; ++n) {
      short8 bv0 = *(const short8*)&Vs[n * 16 + (lane & 15)][(lane >> 4) * 8];
      short8 bv1 = *(const short8*)&Vs[n * 16 + (lane & 15)][32 + (lane >> 4) * 8];
      o[n] = __builtin_amdgcn_mfma_f32_16x16x32_bf16(ap0, bv0, o[n], 0, 0, 0);
      o[n] = __builtin_amdgcn_mfma_f32_16x16x32_bf16(ap1, bv1, o[n], 0, 0, 0);
    }
    __syncthreads();
  }
#pragma unroll
  for (int n = 0; n < 4; ++n)
#pragma unroll
    for (int r = 0; r < 4; ++r) {
      int row = qt * 64 + wid * 16 + (lane >> 4) * 4 + r;
      int col = h * 64 + n * 16 + (lane & 15);
      float v = o[n][r] / lrow[r];
      attnout[((size_t)b * NTOK + row) * 256 + col] = f2bf(v);
    }
}

// ---------------------------------------------------------------- final scatter-back fusion (inverse-map gather)
__global__ __launch_bounds__(256) void final_kernel(
    const float* __restrict__ f_ir, const float* __restrict__ f_vis,
    const float* __restrict__ rirc, const float* __restrict__ rvisc,
    const float* __restrict__ w32, const float* __restrict__ soft,
    const int* __restrict__ invmap, const float* __restrict__ hs_ptr,
    float* __restrict__ out)
{
  __shared__ float tir[64][65], tvis[64][65];
  __shared__ float wl[64], sl[64];
  __shared__ int il[64];
  int n0 = blockIdx.x * 64, c0 = blockIdx.y * 64, b = blockIdx.z;
  int tid = threadIdx.x;
  float hs = hs_ptr[0];
  if (tid < 64) {
    int t = b * NTOK + n0 + tid;
    wl[tid] = w32[t]; sl[tid] = soft[t]; il[tid] = invmap[t];
  }
  __syncthreads();
#pragma unroll
  for (int i = 0; i < 16; ++i) {
    int l = tid + i * 256;
    int r = l >> 6, col = l & 63;
    int ci = il[r];
    if (ci >= 0) {
      size_t idx = ((size_t)b * NTOK + ci) * 256 + c0 + col;
      tir[r][col] = rirc[idx];
      tvis[r][col] = rvisc[idx];
    }
  }
  __syncthreads();
#pragma unroll
  for (int i = 0; i < 16; ++i) {
    int l = tid + i * 256;
    int r = l >> 6, col = l & 63;
    size_t gidx = ((size_t)b * 256 + c0 + r) * NTOK + n0 + col;
    float base = f_ir[gidx] + f_vis[gidx];
    float val;
    if (il[col] >= 0) {
      float ww = wl[col], ss = sl[col];
      float fusion = tir[col][r] * ww + tvis[col][r] * (1.f - ww);
      val = (base + fusion * ss) * (1.f + ss * hs);
    } else {
      val = base;
    }
    out[gidx] = val;
  }
  if (blockIdx.x == 0 && blockIdx.y == 0 && blockIdx.z == 0 && tid == 0)
    out[(size_t)NB * 256 * NTOK] = 0.f;   // aux_loss
}

// ================================================================ host
extern "C" void kernel_launch(void* const* d_in, const int* in_sizes, int n_in,
                              void* d_out, int out_size, void* d_ws, size_t ws_size,
                              hipStream_t stream)
{
  const float* f_ir     = (const float*)d_in[0];
  const float* f_vis    = (const float*)d_in[1];
  const float* agent_w1 = (const float*)d_in[2];
  const float* agent_b1 = (const float*)d_in[3];
  const float* bn_gamma = (const float*)d_in[4];
  const float* bn_beta  = (const float*)d_in[5];
  const float* bn_mean  = (const float*)d_in[6];
  const float* bn_var   = (const float*)d_in[7];
  const float* agent_w2 = (const float*)d_in[8];
  const float* agent_b2 = (const float*)d_in[9];
  const float* hyp_w1   = (const float*)d_in[10];
  const float* hyp_b1   = (const float*)d_in[11];
  const float* hyp_w2   = (const float*)d_in[12];
  const float* hyp_b2   = (const float*)d_in[13];
  int hs_idx = (in_sizes[14] == 1) ? 14 : 34;
  int mix0   = (in_sizes[14] == 1) ? 15 : 14;
  const float* hs_ptr = (const float*)d_in[hs_idx];
  const float* mir_ln_g = (const float*)d_in[mix0 + 0];
  const float* mir_ln_b = (const float*)d_in[mix0 + 1];
  const float* mir_in_w = (const float*)d_in[mix0 + 2];
  const float* mir_in_b = (const float*)d_in[mix0 + 3];
  const float* mir_out_w= (const float*)d_in[mix0 + 4];
  const float* mir_out_b= (const float*)d_in[mix0 + 5];
  const float* mir_f1_w = (const float*)d_in[mix0 + 6];
  const float* mir_f1_b = (const float*)d_in[mix0 + 7];
  const float* mir_f2_w = (const float*)d_in[mix0 + 8];
  const float* mir_f2_b = (const float*)d_in[mix0 + 9];
  const float* mvis_ln_g = (const float*)d_in[mix0 + 10];
  const float* mvis_ln_b = (const float*)d_in[mix0 + 11];
  const float* mvis_in_w = (const float*)d_in[mix0 + 12];
  const float* mvis_in_b = (const float*)d_in[mix0 + 13];
  const float* mvis_out_w= (const float*)d_in[mix0 + 14];
  const float* mvis_out_b= (const float*)d_in[mix0 + 15];
  const float* mvis_f1_w = (const float*)d_in[mix0 + 16];
  const float* mvis_f1_b = (const float*)d_in[mix0 + 17];
  const float* mvis_f2_w = (const float*)d_in[mix0 + 18];
  const float* mvis_f2_b = (const float*)d_in[mix0 + 19];

  auto padded = [](size_t bytes) { return (bytes + 255) & ~(size_t)255; };
  size_t need2 = padded(2 * BNTC * 4)
               + padded(2 * BNTC * 2)
               + 3 * padded(2 * KVSTR * 2)
               + padded(2 * BNTC * 2)
               + padded(2 * BNTC * 4)
               + padded((size_t)2 * 786432 * 2)
               + padded((size_t)512 * 1024 * 2)
               + padded((size_t)BNT * 16 * 4)
               + padded((size_t)BNT * 8)
               + padded(64) + padded(64)
               + 3 * padded((size_t)BNT * 4)
               + padded((size_t)RCAP * 4)
               + 2 * padded((size_t)BNT * 4)
               + 2 * padded(64);
  int zc = (ws_size >= need2 + (1 << 20)) ? 2 : 1;

  char* ws = (char*)d_ws;
  size_t off = 0;
  auto alloc = [&](size_t bytes) {
    size_t o = off;
    off = (off + bytes + 255) & ~(size_t)255;
    return o;
  };
  size_t o_xc    = alloc(2 * BNTC * 4);
  size_t o_xn    = alloc((size_t)zc * BNTC * 2);
  size_t o_q     = alloc((size_t)zc * KVSTR * 2);
  size_t o_k     = alloc((size_t)zc * KVSTR * 2);
  size_t o_vt    = alloc((size_t)zc * KVSTR * 2);
  size_t o_attn  = alloc((size_t)zc * BNTC * 2);
  size_t o_rr    = alloc(2 * BNTC * 4);
  size_t o_wbf   = alloc((size_t)2 * 786432 * 2);
  size_t o_w2s   = alloc((size_t)512 * 1024 * 2);
  size_t o_hp    = alloc((size_t)BNT * 16 * 4);
  size_t o_w64   = alloc((size_t)BNT * 8);
  size_t o_t64   = alloc(64);
  size_t o_count = alloc(64);
  size_t o_w32   = alloc((size_t)BNT * 4);
  size_t o_soft  = alloc((size_t)BNT * 4);
  size_t o_act   = alloc((size_t)BNT * 4);
  size_t o_rlist = alloc((size_t)RCAP * 4);
  size_t o_aidx  = alloc((size_t)BNT * 4);
  size_t o_inv   = alloc((size_t)BNT * 4);
  size_t o_nact  = alloc(64);
  size_t o_npad  = alloc(64);
  (void)n_in; (void)out_size;

  float*  xc   = (float*)(ws + o_xc);
  unsigned short* xn   = (unsigned short*)(ws + o_xn);
  unsigned short* q    = (unsigned short*)(ws + o_q);
  unsigned short* k    = (unsigned short*)(ws + o_k);
  unsigned short* vt   = (unsigned short*)(ws + o_vt);
  unsigned short* attn = (unsigned short*)(ws + o_attn);
  unsigned short* hffn = (unsigned short*)(ws + o_q);
  float*  rr   = (float*)(ws + o_rr);
  unsigned short* A2 = (unsigned short*)(ws + o_rr);   // x_hi [BNT][512]; dead before EPI3 writes
  unsigned short* wbf  = (unsigned short*)(ws + o_wbf);
  unsigned short* W2   = (unsigned short*)(ws + o_w2s);
  float*  hpart = (float*)(ws + o_hp);
  double* w64  = (double*)(ws + o_w64);
  double* t64  = (double*)(ws + o_t64);
  int*    cnt  = (int*)(ws + o_count);
  int*    rcount = cnt + 8;
  float*  w32  = (float*)(ws + o_w32);
  float*  soft = (float*)(ws + o_soft);
  int*    act  = (int*)(ws + o_act);
  int*    rlist = (int*)(ws + o_rlist);
  int*    aidx = (int*)(ws + o_aidx);
  int*    invm = (int*)(ws + o_inv);
  int*    nact = (int*)(ws + o_nact);
  int*    npad = (int*)(ws + o_npad);

  const unsigned short* mir_in  = wbf;
  const unsigned short* mir_out = wbf + 196608;
  const unsigned short* mir_f1  = wbf + 262144;
  const unsigned short* mir_f2  = wbf + 524288;
  const unsigned short* vis_in  = wbf + 786432;
  const unsigned short* vis_out = wbf + 786432 + 196608;
  const unsigned short* vis_f1  = wbf + 786432 + 262144;
  const unsigned short* vis_f2  = wbf + 786432 + 524288;

  // --- independent setup (off the decision chain)
  hipMemsetAsync(cnt, 0, 16 * sizeof(int), stream);
  convert_weights<<<6144, 256, 0, stream>>>(mir_in_w, mir_out_w, mir_f1_w, mir_f2_w,
                                            mvis_in_w, mvis_out_w, mvis_f1_w, mvis_f2_w,
                                            wbf);
  split_w_kernel<<<1024, 256, 0, stream>>>(agent_w1, W2);
  split_x_kernel<<<dim3(36, 8, 8), 256, 0, stream>>>(f_ir, f_vis, A2);

  // --- agent decision chain
  agent_gemm<<<dim3(BNT / 128, 8), 256, 0, stream>>>(
      A2, W2, agent_b1, bn_gamma, bn_beta, bn_mean, bn_var, agent_w2, hpart);
  decide_kernel<<<8, 256, 0, stream>>>(
      hpart, agent_b2, hyp_w1, hyp_b1, hyp_w2, hyp_b2, w64, w32, t64, rcount, rlist);
  refine_kernel<<<RCAP, 1024, 0, stream>>>(
      f_ir, f_vis, agent_w1, agent_b1, bn_gamma, bn_beta, bn_mean, bn_var,
      agent_w2, agent_b2, rlist, rcount, w64, w32);
  compact_kernel<<<8, 256, 0, stream>>>(w64, t64, soft, act, aidx, invm, nact, npad);

  if (zc == 2) {
    size_t WSTR = 786432;
    // fused gather + residual write + first LN (z: 0=ir, 1=vis)
    gatherln_kernel<<<dim3(BNT / 4, 2), 256, 0, stream>>>(
        A2, aidx, npad, mir_ln_g, mir_ln_b, mvis_ln_g, mvis_ln_b, xc, xn);
    gemm_bt<0><<<dim3(BNT / 128, 6, 2), 256, 0, stream>>>(
        xn, BNTC, mir_in, WSTR, mir_in_b, mvis_in_b, 0,
        nullptr, 0, nullptr, 0, nullptr, 0, q, k, vt, KVSTR, npad, 768, 256);
    flash_kernel<<<dim3(32, 36, 2), 256, 0, stream>>>(q, k, vt, nact, npad, attn);
    gemm_bt<1><<<dim3(BNT / 128, 2, 2), 256, 0, stream>>>(
        attn, BNTC, mir_out, WSTR, mir_out_b, mvis_out_b, 0,
        xc, BNTC, nullptr, 0, nullptr, 0, nullptr, nullptr, nullptr, 0, npad, 256, 256);
    ln_kernel<<<dim3(BNT / 4, 2), 256, 0, stream>>>(
        xc, BNTC, mir_ln_g, mir_ln_b, mvis_ln_g, mvis_ln_b, 0, xn, BNTC, npad);
    gemm_bt<2><<<dim3(BNT / 128, 8, 2), 256, 0, stream>>>(
        xn, BNTC, mir_f1, WSTR, mir_f1_b, mvis_f1_b, 0,
        nullptr, 0, nullptr, 0, hffn, HSTR, nullptr, nullptr, nullptr, 0, npad, 1024, 256);
    gemm_bt<3><<<dim3(BNT / 128, 2, 2), 256, 0, stream>>>(
        hffn, HSTR, mir_f2, WSTR, mir_f2_b, mvis_f2_b, 0,
        xc, BNTC, rr, BNTC, nullptr, 0, nullptr, nullptr, nullptr, 0, npad, 256, 1024);
  } else {
    gather_kernel<<<dim3(36, 8, 2), 256, 0, stream>>>(A2, aidx, npad, xc);
    for (int s = 0; s < 2; ++s) {
      const float* g   = s ? mvis_ln_g : mir_ln_g;
      const float* be  = s ? mvis_ln_b : mir_ln_b;
      const unsigned short* w_in  = s ? vis_in  : mir_in;
      const unsigned short* w_out = s ? vis_out : mir_out;
      const unsigned short* w_f1  = s ? vis_f1  : mir_f1;
      const unsigned short* w_f2  = s ? vis_f2  : mir_f2;
      const float* b_in  = s ? mvis_in_b  : mir_in_b;
      const float* b_out = s ? mvis_out_b : mir_out_b;
      const float* b_f1  = s ? mvis_f1_b  : mir_f1_b;
      const float* b_f2  = s ? mvis_f2_b  : mir_f2_b;
      float* xcs = xc + (size_t)s * BNTC;
      float* rrs = rr + (size_t)s * BNTC;
      ln_kernel<<<dim3(BNT / 4, 1), 256, 0, stream>>>(
          xcs, 0, g, be, g, be, 0, xn, 0, npad);
      gemm_bt<0><<<dim3(BNT / 128, 6, 1), 256, 0, stream>>>(
          xn, 0, w_in, 0, b_in, b_in, 0,
          nullptr, 0, nullptr, 0, nullptr, 0, q, k, vt, 0, npad, 768, 256);
      flash_kernel<<<dim3(32, 36, 1), 256, 0, stream>>>(q, k, vt, nact, npad, attn);
      gemm_bt<1><<<dim3(BNT / 128, 2, 1), 256, 0, stream>>>(
          attn, 0, w_out, 0, b_out, b_out, 0,
          xcs, 0, nullptr, 0, nullptr, 0, nullptr, nullptr, nullptr, 0, npad, 256, 256);
      ln_kernel<<<dim3(BNT / 4, 1), 256, 0, stream>>>(
          xcs, 0, g, be, g, be, 0, xn, 0, npad);
      gemm_bt<2><<<dim3(BNT / 128, 8, 1), 256, 0, stream>>>(
          xn, 0, w_f1, 0, b_f1, b_f1, 0,
          nullptr, 0, nullptr, 0, hffn, 0, nullptr, nullptr, nullptr, 0, npad, 1024, 256);
      gemm_bt<3><<<dim3(BNT / 128, 2, 1), 256, 0, stream>>>(
          hffn, 0, w_f2, 0, b_f2, b_f2, 0,
          xcs, 0, rrs, 0, nullptr, 0, nullptr, nullptr, nullptr, 0, npad, 256, 1024);
    }
  }

  // --- final fusion + aux loss
  final_kernel<<<dim3(36, 4, 8), 256, 0, stream>>>(
      f_ir, f_vis, rr, rr + BNTC, w32, soft, invm, hs_ptr, (float*)d_out);
}